// Round 2
// baseline (678.404 us; speedup 1.0000x reference)
//
#include <hip/hip_runtime.h>

#define N_NODES   50000
#define N_EDGES   800000
#define NODE_DIM  128
#define HIDDEN    256
#define LATENT    128
#define COND      5
#define ROWS      32   // rows per GEMM tile

typedef unsigned int uint;
typedef unsigned short ushort;

static __device__ __forceinline__ ushort f32_to_bf16(float f) {
    union { float f; uint u; } v; v.f = f;
    uint r = v.u + 0x7FFF + ((v.u >> 16) & 1);   // round-to-nearest-even
    return (ushort)(r >> 16);
}
static __device__ __forceinline__ float bf16_to_f32(uint h) {
    union { uint u; float f; } v; v.u = h << 16;
    return v.f;
}

// ---------------- CSR build ----------------

__global__ void hist_kernel(const int* __restrict__ dst, int* __restrict__ deg) {
    int e = blockIdx.x * blockDim.x + threadIdx.x;
    if (e < N_EDGES) atomicAdd(&deg[dst[e]], 1);
}

__global__ void scan_kernel(const int* __restrict__ deg, int* __restrict__ offsets,
                            int* __restrict__ cursor) {
    __shared__ int sums[1024];
    const int C = (N_NODES + 1023) / 1024;  // 49
    int t = threadIdx.x;
    int begin = t * C;
    int end   = begin + C < N_NODES ? begin + C : N_NODES;
    int s = 0;
    for (int i = begin; i < end; ++i) s += deg[i];
    sums[t] = s;
    __syncthreads();
    for (int off = 1; off < 1024; off <<= 1) {
        int v = (t >= off) ? sums[t - off] : 0;
        __syncthreads();
        sums[t] += v;
        __syncthreads();
    }
    int running = (t == 0) ? 0 : sums[t - 1];
    for (int i = begin; i < end; ++i) {
        offsets[i] = running;
        cursor[i]  = running;
        running += deg[i];
    }
    if (t == 1023) offsets[N_NODES] = sums[1023];
}

__global__ void scatter_kernel(const int* __restrict__ src, const int* __restrict__ dst,
                               int* __restrict__ cursor, int* __restrict__ csr_src) {
    int e = blockIdx.x * blockDim.x + threadIdx.x;
    if (e < N_EDGES) {
        int pos = atomicAdd(&cursor[dst[e]], 1);
        csr_src[pos] = src[e];
    }
}

// ---------------- fp32 -> bf16 bulk convert ----------------

__global__ void f32_to_bf16_kernel(const float* __restrict__ in, ushort* __restrict__ out, int n4) {
    int i = blockIdx.x * blockDim.x + threadIdx.x;
    if (i < n4) {
        float4 v = reinterpret_cast<const float4*>(in)[i];
        ushort4 o;
        o.x = f32_to_bf16(v.x); o.y = f32_to_bf16(v.y);
        o.z = f32_to_bf16(v.z); o.w = f32_to_bf16(v.w);
        reinterpret_cast<ushort4*>(out)[i] = o;
    }
}

// ---------------- aggregation: one wave per node, bf16 gather, fp32 accum ----------------

template <int D>
__global__ void agg_kernel(const ushort* __restrict__ x, const int* __restrict__ offsets,
                           const int* __restrict__ csr_src, float* __restrict__ agg) {
    int gw   = (blockIdx.x * blockDim.x + threadIdx.x) >> 6;  // node id
    int lane = threadIdx.x & 63;
    if (gw >= N_NODES) return;
    int j0 = offsets[gw], j1 = offsets[gw + 1];
    constexpr int V = D / 64;  // 2 (D=128) or 4 (D=256)
    float acc[V];
#pragma unroll
    for (int i = 0; i < V; ++i) acc[i] = 0.f;
    for (int j = j0; j < j1; ++j) {
        int s = csr_src[j];
        const ushort* row = x + (size_t)s * D + lane * V;
        if constexpr (V == 2) {
            uint u = *reinterpret_cast<const uint*>(row);
            acc[0] += bf16_to_f32(u & 0xFFFFu);
            acc[1] += bf16_to_f32(u >> 16);
        } else {
            uint2 u = *reinterpret_cast<const uint2*>(row);
            acc[0] += bf16_to_f32(u.x & 0xFFFFu);
            acc[1] += bf16_to_f32(u.x >> 16);
            acc[2] += bf16_to_f32(u.y & 0xFFFFu);
            acc[3] += bf16_to_f32(u.y >> 16);
        }
    }
    float* o = agg + (size_t)gw * D + lane * V;
    if constexpr (V == 2) {
        *reinterpret_cast<float2*>(o) = make_float2(acc[0], acc[1]);
    } else {
        *reinterpret_cast<float4*>(o) = make_float4(acc[0], acc[1], acc[2], acc[3]);
    }
}

// ---------------- GEMM: X = relu(A[N,K] @ W[K,256] + b) ----------------
// 32 rows/block, 256 threads, 8x4 micro-tile. POOL=true: column-sum relu output
// into pooled[256] (x2 never materialized). POOL=false: write bf16 X.

template <int K, bool POOL>
__global__ __launch_bounds__(256) void gemm_kernel(const float* __restrict__ A,
                                                   const float* __restrict__ W,
                                                   const float* __restrict__ b,
                                                   ushort* __restrict__ Xbf,
                                                   float* __restrict__ pooled) {
    __shared__ float As[ROWS][K + 4];
    const int t    = threadIdx.x;
    const int row0 = blockIdx.x * ROWS;

    constexpr int F4_PER_ROW = K / 4;             // 32 or 64
    constexpr int PER_THREAD = ROWS * F4_PER_ROW / 256;  // 4 or 8
#pragma unroll
    for (int it = 0; it < PER_THREAD; ++it) {
        int idx = t + it * 256;
        int r   = idx / F4_PER_ROW;
        int kq  = idx % F4_PER_ROW;
        int row = row0 + r;
        float4 v = (row < N_NODES)
                 ? *reinterpret_cast<const float4*>(&A[(size_t)row * K + kq * 4])
                 : make_float4(0.f, 0.f, 0.f, 0.f);
        *reinterpret_cast<float4*>(&As[r][kq * 4]) = v;
    }
    __syncthreads();

    const int tx = t & 63, ty = t >> 6;
    const int j0 = tx * 4;     // output column
    const int r0 = ty * 8;     // first row of this thread's 8
    float acc[8][4] = {};

#pragma unroll 2
    for (int k = 0; k < K; k += 4) {
        float4 w0 = *reinterpret_cast<const float4*>(&W[(size_t)(k + 0) * HIDDEN + j0]);
        float4 w1 = *reinterpret_cast<const float4*>(&W[(size_t)(k + 1) * HIDDEN + j0]);
        float4 w2 = *reinterpret_cast<const float4*>(&W[(size_t)(k + 2) * HIDDEN + j0]);
        float4 w3 = *reinterpret_cast<const float4*>(&W[(size_t)(k + 3) * HIDDEN + j0]);
#pragma unroll
        for (int i = 0; i < 8; ++i) {
            float4 a = *reinterpret_cast<const float4*>(&As[r0 + i][k]);
            acc[i][0] += a.x * w0.x + a.y * w1.x + a.z * w2.x + a.w * w3.x;
            acc[i][1] += a.x * w0.y + a.y * w1.y + a.z * w2.y + a.w * w3.y;
            acc[i][2] += a.x * w0.z + a.y * w1.z + a.z * w2.z + a.w * w3.z;
            acc[i][3] += a.x * w0.w + a.y * w1.w + a.z * w2.w + a.w * w3.w;
        }
    }

    float4 bias = *reinterpret_cast<const float4*>(&b[j0]);
    if constexpr (POOL) {
        __shared__ float red[4][HIDDEN];
        float cs[4] = {0.f, 0.f, 0.f, 0.f};
#pragma unroll
        for (int i = 0; i < 8; ++i) {
            if (row0 + r0 + i < N_NODES) {
                cs[0] += fmaxf(acc[i][0] + bias.x, 0.f);
                cs[1] += fmaxf(acc[i][1] + bias.y, 0.f);
                cs[2] += fmaxf(acc[i][2] + bias.z, 0.f);
                cs[3] += fmaxf(acc[i][3] + bias.w, 0.f);
            }
        }
#pragma unroll
        for (int c = 0; c < 4; ++c) red[ty][j0 + c] = cs[c];
        __syncthreads();
        if (ty == 0) {
#pragma unroll
            for (int c = 0; c < 4; ++c) {
                float s = red[0][j0 + c] + red[1][j0 + c] + red[2][j0 + c] + red[3][j0 + c];
                atomicAdd(&pooled[j0 + c], s);
            }
        }
    } else {
#pragma unroll
        for (int i = 0; i < 8; ++i) {
            int row = row0 + r0 + i;
            if (row < N_NODES) {
                ushort4 o;
                o.x = f32_to_bf16(fmaxf(acc[i][0] + bias.x, 0.f));
                o.y = f32_to_bf16(fmaxf(acc[i][1] + bias.y, 0.f));
                o.z = f32_to_bf16(fmaxf(acc[i][2] + bias.z, 0.f));
                o.w = f32_to_bf16(fmaxf(acc[i][3] + bias.w, 0.f));
                *reinterpret_cast<ushort4*>(&Xbf[(size_t)row * HIDDEN + j0]) = o;
            }
        }
    }
}

// ---------------- head MLP ----------------

__global__ void head_kernel(const float* __restrict__ pooled_sum, const float* __restrict__ cond,
                            const float* __restrict__ Wfc, const float* __restrict__ bfc,
                            const float* __restrict__ Wmean, const float* __restrict__ bmean,
                            const float* __restrict__ Wlogvar, const float* __restrict__ blogvar,
                            float* __restrict__ out) {
    __shared__ float v[HIDDEN + COND];
    __shared__ float h[LATENT];
    int t = threadIdx.x;
    if (t < HIDDEN) v[t] = pooled_sum[t] * (1.0f / N_NODES);
    if (t < COND) v[HIDDEN + t] = cond[t];
    __syncthreads();
    if (t < LATENT) {
        float s = bfc[t];
        for (int k = 0; k < HIDDEN + COND; ++k) s += v[k] * Wfc[k * LATENT + t];
        h[t] = fmaxf(s, 0.f);
    }
    __syncthreads();
    if (t < LATENT) {
        float s = bmean[t];
        for (int k = 0; k < LATENT; ++k) s += h[k] * Wmean[k * LATENT + t];
        out[t] = s;
    } else {
        int j = t - LATENT;
        float s = blogvar[j];
        for (int k = 0; k < LATENT; ++k) s += h[k] * Wlogvar[k * LATENT + j];
        out[LATENT + j] = s;
    }
}

// ---------------- launch ----------------

extern "C" void kernel_launch(void* const* d_in, const int* in_sizes, int n_in,
                              void* d_out, int out_size, void* d_ws, size_t ws_size,
                              hipStream_t stream) {
    const float* node_features = (const float*)d_in[0];
    const float* conditions    = (const float*)d_in[1];
    const int*   src           = (const int*)d_in[2];
    const int*   dst           = (const int*)d_in[3];
    const float* W1  = (const float*)d_in[4];
    const float* b1  = (const float*)d_in[5];
    const float* W2  = (const float*)d_in[6];
    const float* b2  = (const float*)d_in[7];
    const float* Wfc = (const float*)d_in[8];
    const float* bfc = (const float*)d_in[9];
    const float* Wmean   = (const float*)d_in[10];
    const float* bmean   = (const float*)d_in[11];
    const float* Wlogvar = (const float*)d_in[12];
    const float* blogvar = (const float*)d_in[13];
    float* out = (float*)d_out;

    // workspace layout (256B aligned slices); lifetimes:
    //   x1_bf16   [0, 25.6MB)        live gemm1 -> agg2
    //   nf_bf16   [25.6, 38.4)       live convert -> agg1
    //   agg1      [38.4, 64.0)       live agg1 -> gemm1
    //   agg2      [25.6, 76.8)       live agg2 -> gemm2 (overlaps dead nf_bf16/agg1)
    size_t o = 0;
    auto alloc = [&](size_t bytes) {
        void* p = (char*)d_ws + o;
        o += (bytes + 255) & ~(size_t)255;
        return p;
    };
    int* deg      = (int*)alloc((size_t)N_NODES * 4);
    int* offsets  = (int*)alloc((size_t)(N_NODES + 1) * 4);
    int* cursor   = (int*)alloc((size_t)N_NODES * 4);
    int* csr_src  = (int*)alloc((size_t)N_EDGES * 4);
    float* pooled = (float*)alloc(HIDDEN * 4);
    char* big     = (char*)alloc((size_t)N_NODES * HIDDEN * 4 + (size_t)N_NODES * HIDDEN * 2);

    ushort* x1_bf16 = (ushort*)big;                                        // 25.6 MB
    ushort* nf_bf16 = (ushort*)(big + (size_t)N_NODES * HIDDEN * 2);       // 12.8 MB
    float*  agg1    = (float*)(big + (size_t)N_NODES * HIDDEN * 2
                                   + (size_t)N_NODES * NODE_DIM * 2);      // 25.6 MB
    float*  agg2    = (float*)(big + (size_t)N_NODES * HIDDEN * 2);        // 51.2 MB

    hipMemsetAsync(deg, 0, (size_t)N_NODES * 4, stream);
    hipMemsetAsync(pooled, 0, HIDDEN * 4, stream);

    hist_kernel<<<(N_EDGES + 255) / 256, 256, 0, stream>>>(dst, deg);
    scan_kernel<<<1, 1024, 0, stream>>>(deg, offsets, cursor);
    scatter_kernel<<<(N_EDGES + 255) / 256, 256, 0, stream>>>(src, dst, cursor, csr_src);

    // convert node features to bf16 for the gather
    f32_to_bf16_kernel<<<(N_NODES * NODE_DIM / 4 + 255) / 256, 256, 0, stream>>>(
        node_features, nf_bf16, N_NODES * NODE_DIM / 4);

    const int GEMM_GRID = (N_NODES + ROWS - 1) / ROWS;  // 1563

    // layer 1
    agg_kernel<NODE_DIM><<<(N_NODES * 64) / 256, 256, 0, stream>>>(nf_bf16, offsets, csr_src, agg1);
    gemm_kernel<NODE_DIM, false><<<GEMM_GRID, 256, 0, stream>>>(agg1, W1, b1, x1_bf16, nullptr);

    // layer 2 (+ fused mean-pool)
    agg_kernel<HIDDEN><<<(N_NODES * 64) / 256, 256, 0, stream>>>(x1_bf16, offsets, csr_src, agg2);
    gemm_kernel<HIDDEN, true><<<GEMM_GRID, 256, 0, stream>>>(agg2, W2, b2, nullptr, pooled);

    head_kernel<<<1, 256, 0, stream>>>(pooled, conditions, Wfc, bfc,
                                       Wmean, bmean, Wlogvar, blogvar, out);
}

// Round 3
// 409.249 us; speedup vs baseline: 1.6577x; 1.6577x over previous
//
#include <hip/hip_runtime.h>

#define N_NODES   50000
#define N_EDGES   800000
#define NODE_DIM  128
#define HIDDEN    256
#define LATENT    128
#define COND      5

typedef unsigned int uint;
typedef unsigned short ushort;

typedef __attribute__((ext_vector_type(8))) short bf16x8;
typedef __attribute__((ext_vector_type(4))) float f32x4;

static __device__ __forceinline__ ushort f32_to_bf16(float f) {
    union { float f; uint u; } v; v.f = f;
    uint r = v.u + 0x7FFF + ((v.u >> 16) & 1);   // RNE
    return (ushort)(r >> 16);
}
static __device__ __forceinline__ float bf16_to_f32(uint h) {
    union { uint u; float f; } v; v.u = h << 16;
    return v.f;
}
static __device__ __forceinline__ uint pack_bf16(float lo, float hi) {
    return (uint)f32_to_bf16(lo) | ((uint)f32_to_bf16(hi) << 16);
}

// ---------------- CSR build ----------------

__global__ void hist_kernel(const int* __restrict__ dst, int* __restrict__ deg) {
    int e = blockIdx.x * blockDim.x + threadIdx.x;
    if (e < N_EDGES) atomicAdd(&deg[dst[e]], 1);
}

__global__ void scan_kernel(const int* __restrict__ deg, int* __restrict__ offsets,
                            int* __restrict__ cursor) {
    __shared__ int sums[1024];
    const int C = (N_NODES + 1023) / 1024;  // 49
    int t = threadIdx.x;
    int begin = t * C;
    int end   = begin + C < N_NODES ? begin + C : N_NODES;
    int s = 0;
    for (int i = begin; i < end; ++i) s += deg[i];
    sums[t] = s;
    __syncthreads();
    for (int off = 1; off < 1024; off <<= 1) {
        int v = (t >= off) ? sums[t - off] : 0;
        __syncthreads();
        sums[t] += v;
        __syncthreads();
    }
    int running = (t == 0) ? 0 : sums[t - 1];
    for (int i = begin; i < end; ++i) {
        offsets[i] = running;
        cursor[i]  = running;
        running += deg[i];
    }
    if (t == 1023) offsets[N_NODES] = sums[1023];
}

__global__ void scatter_kernel(const int* __restrict__ src, const int* __restrict__ dst,
                               int* __restrict__ cursor, int* __restrict__ csr_src) {
    int e = blockIdx.x * blockDim.x + threadIdx.x;
    if (e < N_EDGES) {
        int pos = atomicAdd(&cursor[dst[e]], 1);
        csr_src[pos] = src[e];
    }
}

// ---------------- prep: nf -> bf16, W1/W2 -> transposed bf16 ----------------

#define NF4 (N_NODES * NODE_DIM / 4)   // 1,600,000 float4 groups

__global__ void prep_kernel(const float* __restrict__ nf,
                            const float* __restrict__ W1, const float* __restrict__ W2,
                            ushort* __restrict__ nf_bf,
                            ushort* __restrict__ Wt1, ushort* __restrict__ Wt2) {
    int id = blockIdx.x * blockDim.x + threadIdx.x;
    if (id < NF4) {
        float4 v = reinterpret_cast<const float4*>(nf)[id];
        ushort4 o;
        o.x = f32_to_bf16(v.x); o.y = f32_to_bf16(v.y);
        o.z = f32_to_bf16(v.z); o.w = f32_to_bf16(v.w);
        reinterpret_cast<ushort4*>(nf_bf)[id] = o;
    } else if (id < NF4 + NODE_DIM * HIDDEN) {           // W1 [128,256] -> Wt1 [256,128]
        int i = id - NF4;
        int k = i >> 8, c = i & 255;
        Wt1[c * NODE_DIM + k] = f32_to_bf16(W1[i]);
    } else if (id < NF4 + NODE_DIM * HIDDEN + HIDDEN * HIDDEN) {  // W2 [256,256] -> Wt2 [256,256]
        int i = id - NF4 - NODE_DIM * HIDDEN;
        int k = i >> 8, c = i & 255;
        Wt2[c * HIDDEN + k] = f32_to_bf16(W2[i]);
    }
}

// ---------------- aggregation: 16-lane group per node, bf16 in/out, fp32 accum ----------------

template <int D>
__global__ void agg_kernel(const ushort* __restrict__ x, const int* __restrict__ offsets,
                           const int* __restrict__ csr_src, ushort* __restrict__ out) {
    constexpr int EPL = D / 16;        // elements per lane: 8 or 16
    int tid   = blockIdx.x * blockDim.x + threadIdx.x;
    int node  = tid >> 4;
    int gl    = threadIdx.x & 15;
    int lane  = threadIdx.x & 63;
    int gbase = lane & ~15;
    if (node >= N_NODES) return;
    int j0 = offsets[node], j1 = offsets[node + 1];

    float acc[EPL];
#pragma unroll
    for (int i = 0; i < EPL; ++i) acc[i] = 0.f;

    const size_t lane_off = (size_t)gl * EPL;

    auto body = [&](int s) {
        const uint4* p = reinterpret_cast<const uint4*>(x + (size_t)s * D + lane_off);
        uint4 u = p[0];
        acc[0] += bf16_to_f32(u.x & 0xFFFFu); acc[1] += bf16_to_f32(u.x >> 16);
        acc[2] += bf16_to_f32(u.y & 0xFFFFu); acc[3] += bf16_to_f32(u.y >> 16);
        acc[4] += bf16_to_f32(u.z & 0xFFFFu); acc[5] += bf16_to_f32(u.z >> 16);
        acc[6] += bf16_to_f32(u.w & 0xFFFFu); acc[7] += bf16_to_f32(u.w >> 16);
        if constexpr (EPL == 16) {
            uint4 u2 = p[1];
            acc[8]  += bf16_to_f32(u2.x & 0xFFFFu); acc[9]  += bf16_to_f32(u2.x >> 16);
            acc[10] += bf16_to_f32(u2.y & 0xFFFFu); acc[11] += bf16_to_f32(u2.y >> 16);
            acc[12] += bf16_to_f32(u2.z & 0xFFFFu); acc[13] += bf16_to_f32(u2.z >> 16);
            acc[14] += bf16_to_f32(u2.w & 0xFFFFu); acc[15] += bf16_to_f32(u2.w >> 16);
        }
    };

    for (int jb = j0; jb < j1; jb += 16) {
        int idx = (jb + gl < j1) ? csr_src[jb + gl] : 0;
        if (j1 - jb >= 16) {
#pragma unroll
            for (int i = 0; i < 16; ++i) body(__shfl(idx, gbase + i));
        } else {
            int cnt = j1 - jb;
            for (int i = 0; i < cnt; ++i) body(__shfl(idx, gbase + i));
        }
    }

    uint4* op = reinterpret_cast<uint4*>(out + (size_t)node * D + lane_off);
    uint4 o0;
    o0.x = pack_bf16(acc[0], acc[1]); o0.y = pack_bf16(acc[2], acc[3]);
    o0.z = pack_bf16(acc[4], acc[5]); o0.w = pack_bf16(acc[6], acc[7]);
    op[0] = o0;
    if constexpr (EPL == 16) {
        uint4 o1;
        o1.x = pack_bf16(acc[8],  acc[9]);  o1.y = pack_bf16(acc[10], acc[11]);
        o1.z = pack_bf16(acc[12], acc[13]); o1.w = pack_bf16(acc[14], acc[15]);
        op[1] = o1;
    }
}

// ---------------- MFMA GEMM: X = relu(A[M,K]bf16 @ W[K,256] + b), LDS-free ----------------
// block = 64 rows x 256 cols, 4 waves; wave = 64x64 (4x4 fragments of 16x16x32).
// A row-major bf16; Wt = W^T [256,K] row-major bf16 (so B-frags are contiguous).
// POOL: column-sum of relu output into pooled[256]; else store bf16 X.

template <int K, bool POOL>
__global__ __launch_bounds__(256) void gemm_mfma_kernel(const ushort* __restrict__ A,
                                                        const ushort* __restrict__ Wt,
                                                        const float* __restrict__ bias,
                                                        ushort* __restrict__ Xout,
                                                        float* __restrict__ pooled) {
    const int lane = threadIdx.x & 63;
    const int wv   = threadIdx.x >> 6;       // 0..3
    const int row0 = blockIdx.x * 64;
    const int col0 = wv * 64;
    const int fr   = lane & 15;              // fragment row (A) / col (B)
    const int kg   = (lane >> 4) * 8;        // fragment k-offset

    const bf16x8 zero8 = {0, 0, 0, 0, 0, 0, 0, 0};
    f32x4 acc[4][4];
#pragma unroll
    for (int rt = 0; rt < 4; ++rt)
#pragma unroll
        for (int ct = 0; ct < 4; ++ct)
            acc[rt][ct] = (f32x4){0.f, 0.f, 0.f, 0.f};

#pragma unroll
    for (int k0 = 0; k0 < K; k0 += 32) {
        bf16x8 af[4], bfv[4];
#pragma unroll
        for (int rt = 0; rt < 4; ++rt) {
            int r = row0 + rt * 16 + fr;
            af[rt] = (r < N_NODES)
                   ? *reinterpret_cast<const bf16x8*>(A + (size_t)r * K + k0 + kg)
                   : zero8;
        }
#pragma unroll
        for (int ct = 0; ct < 4; ++ct) {
            int c = col0 + ct * 16 + fr;
            bfv[ct] = *reinterpret_cast<const bf16x8*>(Wt + (size_t)c * K + k0 + kg);
        }
#pragma unroll
        for (int rt = 0; rt < 4; ++rt)
#pragma unroll
            for (int ct = 0; ct < 4; ++ct)
                acc[rt][ct] = __builtin_amdgcn_mfma_f32_16x16x32_bf16(af[rt], bfv[ct], acc[rt][ct], 0, 0, 0);
    }

    // D element (m,n): m = row0 + rt*16 + (lane>>4)*4 + e,  n = col0 + ct*16 + (lane&15)
    float bcol[4];
#pragma unroll
    for (int ct = 0; ct < 4; ++ct) bcol[ct] = bias[col0 + ct * 16 + fr];

    const int mrow = (lane >> 4) * 4;

    if constexpr (POOL) {
        float cs[4] = {0.f, 0.f, 0.f, 0.f};
#pragma unroll
        for (int rt = 0; rt < 4; ++rt) {
#pragma unroll
            for (int e = 0; e < 4; ++e) {
                int m = row0 + rt * 16 + mrow + e;
                if (m < N_NODES) {
#pragma unroll
                    for (int ct = 0; ct < 4; ++ct)
                        cs[ct] += fmaxf(acc[rt][ct][e] + bcol[ct], 0.f);
                }
            }
        }
#pragma unroll
        for (int ct = 0; ct < 4; ++ct) {
            cs[ct] += __shfl_xor(cs[ct], 16);
            cs[ct] += __shfl_xor(cs[ct], 32);
        }
        if (lane < 16) {
#pragma unroll
            for (int ct = 0; ct < 4; ++ct)
                atomicAdd(&pooled[col0 + ct * 16 + lane], cs[ct]);
        }
    } else {
#pragma unroll
        for (int rt = 0; rt < 4; ++rt) {
#pragma unroll
            for (int e = 0; e < 4; ++e) {
                int m = row0 + rt * 16 + mrow + e;
                if (m < N_NODES) {
#pragma unroll
                    for (int ct = 0; ct < 4; ++ct) {
                        float v = fmaxf(acc[rt][ct][e] + bcol[ct], 0.f);
                        Xout[(size_t)m * HIDDEN + col0 + ct * 16 + fr] = f32_to_bf16(v);
                    }
                }
            }
        }
    }
}

// ---------------- head MLP ----------------

__global__ void head_kernel(const float* __restrict__ pooled_sum, const float* __restrict__ cond,
                            const float* __restrict__ Wfc, const float* __restrict__ bfc,
                            const float* __restrict__ Wmean, const float* __restrict__ bmean,
                            const float* __restrict__ Wlogvar, const float* __restrict__ blogvar,
                            float* __restrict__ out) {
    __shared__ float v[HIDDEN + COND];
    __shared__ float h[LATENT];
    int t = threadIdx.x;
    if (t < HIDDEN) v[t] = pooled_sum[t] * (1.0f / N_NODES);
    if (t < COND) v[HIDDEN + t] = cond[t];
    __syncthreads();
    if (t < LATENT) {
        float s = bfc[t];
        for (int k = 0; k < HIDDEN + COND; ++k) s += v[k] * Wfc[k * LATENT + t];
        h[t] = fmaxf(s, 0.f);
    }
    __syncthreads();
    if (t < LATENT) {
        float s = bmean[t];
        for (int k = 0; k < LATENT; ++k) s += h[k] * Wmean[k * LATENT + t];
        out[t] = s;
    } else {
        int j = t - LATENT;
        float s = blogvar[j];
        for (int k = 0; k < LATENT; ++k) s += h[k] * Wlogvar[k * LATENT + j];
        out[LATENT + j] = s;
    }
}

// ---------------- launch ----------------

extern "C" void kernel_launch(void* const* d_in, const int* in_sizes, int n_in,
                              void* d_out, int out_size, void* d_ws, size_t ws_size,
                              hipStream_t stream) {
    const float* node_features = (const float*)d_in[0];
    const float* conditions    = (const float*)d_in[1];
    const int*   src           = (const int*)d_in[2];
    const int*   dst           = (const int*)d_in[3];
    const float* W1  = (const float*)d_in[4];
    const float* b1  = (const float*)d_in[5];
    const float* W2  = (const float*)d_in[6];
    const float* b2  = (const float*)d_in[7];
    const float* Wfc = (const float*)d_in[8];
    const float* bfc = (const float*)d_in[9];
    const float* Wmean   = (const float*)d_in[10];
    const float* bmean   = (const float*)d_in[11];
    const float* Wlogvar = (const float*)d_in[12];
    const float* blogvar = (const float*)d_in[13];
    float* out = (float*)d_out;

    size_t o = 0;
    auto alloc = [&](size_t bytes) {
        void* p = (char*)d_ws + o;
        o += (bytes + 255) & ~(size_t)255;
        return p;
    };
    int* deg      = (int*)alloc((size_t)N_NODES * 4);
    int* offsets  = (int*)alloc((size_t)(N_NODES + 1) * 4);
    int* cursor   = (int*)alloc((size_t)N_NODES * 4);
    int* csr_src  = (int*)alloc((size_t)N_EDGES * 4);
    float* pooled = (float*)alloc(HIDDEN * 4);
    ushort* Wt1   = (ushort*)alloc((size_t)HIDDEN * NODE_DIM * 2);   // 64 KB
    ushort* Wt2   = (ushort*)alloc((size_t)HIDDEN * HIDDEN * 2);     // 128 KB
    ushort* nf_bf = (ushort*)alloc((size_t)N_NODES * NODE_DIM * 2);  // 12.8 MB
    ushort* agg1  = (ushort*)alloc((size_t)N_NODES * NODE_DIM * 2);  // 12.8 MB
    ushort* x1    = (ushort*)alloc((size_t)N_NODES * HIDDEN * 2);    // 25.6 MB
    ushort* agg2  = (ushort*)alloc((size_t)N_NODES * HIDDEN * 2);    // 25.6 MB

    hipMemsetAsync(deg, 0, (size_t)N_NODES * 4, stream);
    hipMemsetAsync(pooled, 0, HIDDEN * 4, stream);

    prep_kernel<<<(NF4 + NODE_DIM * HIDDEN + HIDDEN * HIDDEN) / 256, 256, 0, stream>>>(
        node_features, W1, W2, nf_bf, Wt1, Wt2);

    hist_kernel<<<N_EDGES / 256, 256, 0, stream>>>(dst, deg);
    scan_kernel<<<1, 1024, 0, stream>>>(deg, offsets, cursor);
    scatter_kernel<<<N_EDGES / 256, 256, 0, stream>>>(src, dst, cursor, csr_src);

    const int GEMM_GRID = (N_NODES + 63) / 64;  // 782

    // layer 1
    agg_kernel<NODE_DIM><<<N_NODES * 16 / 256, 256, 0, stream>>>(nf_bf, offsets, csr_src, agg1);
    gemm_mfma_kernel<NODE_DIM, false><<<GEMM_GRID, 256, 0, stream>>>(agg1, Wt1, b1, x1, nullptr);

    // layer 2 (+ fused mean-pool)
    agg_kernel<HIDDEN><<<N_NODES * 16 / 256, 256, 0, stream>>>(x1, offsets, csr_src, agg2);
    gemm_mfma_kernel<HIDDEN, true><<<GEMM_GRID, 256, 0, stream>>>(agg2, Wt2, b2, nullptr, pooled);

    head_kernel<<<1, 256, 0, stream>>>(pooled, conditions, Wfc, bfc,
                                       Wmean, bmean, Wlogvar, blogvar, out);
}

// Round 4
// 308.293 us; speedup vs baseline: 2.2005x; 1.3275x over previous
//
#include <hip/hip_runtime.h>

#define N_NODES   50000
#define N_EDGES   800000
#define NODE_DIM  128
#define HIDDEN    256
#define LATENT    128
#define COND      5

#define SCAN_BLOCKS ((N_NODES + 255) / 256)   // 196

typedef unsigned int uint;
typedef unsigned short ushort;

typedef __attribute__((ext_vector_type(8))) short bf16x8;
typedef __attribute__((ext_vector_type(4))) float f32x4;

static __device__ __forceinline__ ushort f32_to_bf16(float f) {
    union { float f; uint u; } v; v.f = f;
    uint r = v.u + 0x7FFF + ((v.u >> 16) & 1);   // RNE
    return (ushort)(r >> 16);
}
static __device__ __forceinline__ float bf16_to_f32(uint h) {
    union { uint u; float f; } v; v.u = h << 16;
    return v.f;
}
static __device__ __forceinline__ uint pack_bf16(float lo, float hi) {
    return (uint)f32_to_bf16(lo) | ((uint)f32_to_bf16(hi) << 16);
}

// ---------------- CSR build ----------------

__global__ void hist_kernel(const int* __restrict__ dst, int* __restrict__ deg) {
    int e = blockIdx.x * blockDim.x + threadIdx.x;
    if (e < N_EDGES) atomicAdd(&deg[dst[e]], 1);
}

// phase A: per-block inclusive scan (256 elems/block) + block totals
__global__ void scan_a_kernel(const int* __restrict__ deg, int* __restrict__ incl,
                              int* __restrict__ blocksums) {
    int i = blockIdx.x * 256 + threadIdx.x;
    int lane = threadIdx.x & 63;
    int w    = threadIdx.x >> 6;
    int v = (i < N_NODES) ? deg[i] : 0;
    int s = v;
#pragma unroll
    for (int d = 1; d < 64; d <<= 1) {
        int t = __shfl_up(s, d);
        if (lane >= d) s += t;
    }
    __shared__ int wsum[4];
    if (lane == 63) wsum[w] = s;
    __syncthreads();
    int add = 0;
    for (int k = 0; k < w; ++k) add += wsum[k];
    s += add;
    if (i < N_NODES) incl[i] = s;
    if (threadIdx.x == 255) blocksums[blockIdx.x] = s;
}

// phase B: single small block scans the 196 block totals (exclusive)
__global__ void scan_b_kernel(const int* __restrict__ blocksums, int* __restrict__ blockoff) {
    __shared__ int s[256];
    int t = threadIdx.x;
    s[t] = (t < SCAN_BLOCKS) ? blocksums[t] : 0;
    __syncthreads();
    for (int off = 1; off < 256; off <<= 1) {
        int v = (t >= off) ? s[t - off] : 0;
        __syncthreads();
        s[t] += v;
        __syncthreads();
    }
    blockoff[t] = (t == 0) ? 0 : s[t - 1];
}

// phase C: offsets/cursor = blockoff + incl - deg
__global__ void scan_c_kernel(const int* __restrict__ deg, const int* __restrict__ incl,
                              const int* __restrict__ blockoff,
                              int* __restrict__ offsets, int* __restrict__ cursor) {
    int i = blockIdx.x * 256 + threadIdx.x;
    if (i < N_NODES) {
        int inc = incl[i];
        int off = blockoff[blockIdx.x] + inc - deg[i];
        offsets[i] = off;
        cursor[i]  = off;
        if (i == N_NODES - 1) offsets[N_NODES] = blockoff[blockIdx.x] + inc;
    }
}

__global__ void scatter_kernel(const int* __restrict__ src, const int* __restrict__ dst,
                               int* __restrict__ cursor, int* __restrict__ csr_src) {
    int e = blockIdx.x * blockDim.x + threadIdx.x;
    if (e < N_EDGES) {
        int pos = atomicAdd(&cursor[dst[e]], 1);
        csr_src[pos] = src[e];
    }
}

// ---------------- prep: nf -> bf16, W1/W2 -> transposed bf16 ----------------

#define NF4 (N_NODES * NODE_DIM / 4)   // 1,600,000 float4 groups

__global__ void prep_kernel(const float* __restrict__ nf,
                            const float* __restrict__ W1, const float* __restrict__ W2,
                            ushort* __restrict__ nf_bf,
                            ushort* __restrict__ Wt1, ushort* __restrict__ Wt2) {
    int id = blockIdx.x * blockDim.x + threadIdx.x;
    if (id < NF4) {
        float4 v = reinterpret_cast<const float4*>(nf)[id];
        ushort4 o;
        o.x = f32_to_bf16(v.x); o.y = f32_to_bf16(v.y);
        o.z = f32_to_bf16(v.z); o.w = f32_to_bf16(v.w);
        reinterpret_cast<ushort4*>(nf_bf)[id] = o;
    } else if (id < NF4 + NODE_DIM * HIDDEN) {           // W1 [128,256] -> Wt1 [256,128]
        int i = id - NF4;
        int k = i >> 8, c = i & 255;
        Wt1[c * NODE_DIM + k] = f32_to_bf16(W1[i]);
    } else if (id < NF4 + NODE_DIM * HIDDEN + HIDDEN * HIDDEN) {  // W2 [256,256] -> Wt2 [256,256]
        int i = id - NF4 - NODE_DIM * HIDDEN;
        int k = i >> 8, c = i & 255;
        Wt2[c * HIDDEN + k] = f32_to_bf16(W2[i]);
    }
}

// ---------------- aggregation: 16-lane group per node, bf16 in/out, fp32 accum ----------------

template <int D>
__global__ void agg_kernel(const ushort* __restrict__ x, const int* __restrict__ offsets,
                           const int* __restrict__ csr_src, ushort* __restrict__ out) {
    constexpr int EPL = D / 16;        // elements per lane: 8 or 16
    int tid   = blockIdx.x * blockDim.x + threadIdx.x;
    int node  = tid >> 4;
    int gl    = threadIdx.x & 15;
    int lane  = threadIdx.x & 63;
    int gbase = lane & ~15;
    if (node >= N_NODES) return;
    int j0 = offsets[node], j1 = offsets[node + 1];

    float acc[EPL];
#pragma unroll
    for (int i = 0; i < EPL; ++i) acc[i] = 0.f;

    const size_t lane_off = (size_t)gl * EPL;

    auto body = [&](int s) {
        const uint4* p = reinterpret_cast<const uint4*>(x + (size_t)s * D + lane_off);
        uint4 u = p[0];
        acc[0] += bf16_to_f32(u.x & 0xFFFFu); acc[1] += bf16_to_f32(u.x >> 16);
        acc[2] += bf16_to_f32(u.y & 0xFFFFu); acc[3] += bf16_to_f32(u.y >> 16);
        acc[4] += bf16_to_f32(u.z & 0xFFFFu); acc[5] += bf16_to_f32(u.z >> 16);
        acc[6] += bf16_to_f32(u.w & 0xFFFFu); acc[7] += bf16_to_f32(u.w >> 16);
        if constexpr (EPL == 16) {
            uint4 u2 = p[1];
            acc[8]  += bf16_to_f32(u2.x & 0xFFFFu); acc[9]  += bf16_to_f32(u2.x >> 16);
            acc[10] += bf16_to_f32(u2.y & 0xFFFFu); acc[11] += bf16_to_f32(u2.y >> 16);
            acc[12] += bf16_to_f32(u2.z & 0xFFFFu); acc[13] += bf16_to_f32(u2.z >> 16);
            acc[14] += bf16_to_f32(u2.w & 0xFFFFu); acc[15] += bf16_to_f32(u2.w >> 16);
        }
    };

    for (int jb = j0; jb < j1; jb += 16) {
        int idx = (jb + gl < j1) ? csr_src[jb + gl] : 0;
        if (j1 - jb >= 16) {
#pragma unroll
            for (int i = 0; i < 16; ++i) body(__shfl(idx, gbase + i));
        } else {
            int cnt = j1 - jb;
            for (int i = 0; i < cnt; ++i) body(__shfl(idx, gbase + i));
        }
    }

    uint4* op = reinterpret_cast<uint4*>(out + (size_t)node * D + lane_off);
    uint4 o0;
    o0.x = pack_bf16(acc[0], acc[1]); o0.y = pack_bf16(acc[2], acc[3]);
    o0.z = pack_bf16(acc[4], acc[5]); o0.w = pack_bf16(acc[6], acc[7]);
    op[0] = o0;
    if constexpr (EPL == 16) {
        uint4 o1;
        o1.x = pack_bf16(acc[8],  acc[9]);  o1.y = pack_bf16(acc[10], acc[11]);
        o1.z = pack_bf16(acc[12], acc[13]); o1.w = pack_bf16(acc[14], acc[15]);
        op[1] = o1;
    }
}

// ---------------- MFMA GEMM: X = relu(A[M,K]bf16 @ W[K,256] + b), LDS-free ----------------

template <int K, bool POOL>
__global__ __launch_bounds__(256) void gemm_mfma_kernel(const ushort* __restrict__ A,
                                                        const ushort* __restrict__ Wt,
                                                        const float* __restrict__ bias,
                                                        ushort* __restrict__ Xout,
                                                        float* __restrict__ pooled) {
    const int lane = threadIdx.x & 63;
    const int wv   = threadIdx.x >> 6;       // 0..3
    const int row0 = blockIdx.x * 64;
    const int col0 = wv * 64;
    const int fr   = lane & 15;              // fragment row (A) / col (B)
    const int kg   = (lane >> 4) * 8;        // fragment k-offset

    const bf16x8 zero8 = {0, 0, 0, 0, 0, 0, 0, 0};
    f32x4 acc[4][4];
#pragma unroll
    for (int rt = 0; rt < 4; ++rt)
#pragma unroll
        for (int ct = 0; ct < 4; ++ct)
            acc[rt][ct] = (f32x4){0.f, 0.f, 0.f, 0.f};

#pragma unroll
    for (int k0 = 0; k0 < K; k0 += 32) {
        bf16x8 af[4], bfv[4];
#pragma unroll
        for (int rt = 0; rt < 4; ++rt) {
            int r = row0 + rt * 16 + fr;
            af[rt] = (r < N_NODES)
                   ? *reinterpret_cast<const bf16x8*>(A + (size_t)r * K + k0 + kg)
                   : zero8;
        }
#pragma unroll
        for (int ct = 0; ct < 4; ++ct) {
            int c = col0 + ct * 16 + fr;
            bfv[ct] = *reinterpret_cast<const bf16x8*>(Wt + (size_t)c * K + k0 + kg);
        }
#pragma unroll
        for (int rt = 0; rt < 4; ++rt)
#pragma unroll
            for (int ct = 0; ct < 4; ++ct)
                acc[rt][ct] = __builtin_amdgcn_mfma_f32_16x16x32_bf16(af[rt], bfv[ct], acc[rt][ct], 0, 0, 0);
    }

    float bcol[4];
#pragma unroll
    for (int ct = 0; ct < 4; ++ct) bcol[ct] = bias[col0 + ct * 16 + fr];

    const int mrow = (lane >> 4) * 4;

    if constexpr (POOL) {
        float cs[4] = {0.f, 0.f, 0.f, 0.f};
#pragma unroll
        for (int rt = 0; rt < 4; ++rt) {
#pragma unroll
            for (int e = 0; e < 4; ++e) {
                int m = row0 + rt * 16 + mrow + e;
                if (m < N_NODES) {
#pragma unroll
                    for (int ct = 0; ct < 4; ++ct)
                        cs[ct] += fmaxf(acc[rt][ct][e] + bcol[ct], 0.f);
                }
            }
        }
#pragma unroll
        for (int ct = 0; ct < 4; ++ct) {
            cs[ct] += __shfl_xor(cs[ct], 16);
            cs[ct] += __shfl_xor(cs[ct], 32);
        }
        if (lane < 16) {
#pragma unroll
            for (int ct = 0; ct < 4; ++ct)
                atomicAdd(&pooled[col0 + ct * 16 + lane], cs[ct]);
        }
    } else {
#pragma unroll
        for (int rt = 0; rt < 4; ++rt) {
#pragma unroll
            for (int e = 0; e < 4; ++e) {
                int m = row0 + rt * 16 + mrow + e;
                if (m < N_NODES) {
#pragma unroll
                    for (int ct = 0; ct < 4; ++ct) {
                        float v = fmaxf(acc[rt][ct][e] + bcol[ct], 0.f);
                        Xout[(size_t)m * HIDDEN + col0 + ct * 16 + fr] = f32_to_bf16(v);
                    }
                }
            }
        }
    }
}

// ---------------- head MLP ----------------

__global__ void head_kernel(const float* __restrict__ pooled_sum, const float* __restrict__ cond,
                            const float* __restrict__ Wfc, const float* __restrict__ bfc,
                            const float* __restrict__ Wmean, const float* __restrict__ bmean,
                            const float* __restrict__ Wlogvar, const float* __restrict__ blogvar,
                            float* __restrict__ out) {
    __shared__ float v[HIDDEN + COND];
    __shared__ float h[LATENT];
    int t = threadIdx.x;
    if (t < HIDDEN) v[t] = pooled_sum[t] * (1.0f / N_NODES);
    if (t < COND) v[HIDDEN + t] = cond[t];
    __syncthreads();
    if (t < LATENT) {
        float s = bfc[t];
        for (int k = 0; k < HIDDEN + COND; ++k) s += v[k] * Wfc[k * LATENT + t];
        h[t] = fmaxf(s, 0.f);
    }
    __syncthreads();
    if (t < LATENT) {
        float s = bmean[t];
        for (int k = 0; k < LATENT; ++k) s += h[k] * Wmean[k * LATENT + t];
        out[t] = s;
    } else {
        int j = t - LATENT;
        float s = blogvar[j];
        for (int k = 0; k < LATENT; ++k) s += h[k] * Wlogvar[k * LATENT + j];
        out[LATENT + j] = s;
    }
}

// ---------------- launch ----------------

extern "C" void kernel_launch(void* const* d_in, const int* in_sizes, int n_in,
                              void* d_out, int out_size, void* d_ws, size_t ws_size,
                              hipStream_t stream) {
    const float* node_features = (const float*)d_in[0];
    const float* conditions    = (const float*)d_in[1];
    const int*   src           = (const int*)d_in[2];
    const int*   dst           = (const int*)d_in[3];
    const float* W1  = (const float*)d_in[4];
    const float* b1  = (const float*)d_in[5];
    const float* W2  = (const float*)d_in[6];
    const float* b2  = (const float*)d_in[7];
    const float* Wfc = (const float*)d_in[8];
    const float* bfc = (const float*)d_in[9];
    const float* Wmean   = (const float*)d_in[10];
    const float* bmean   = (const float*)d_in[11];
    const float* Wlogvar = (const float*)d_in[12];
    const float* blogvar = (const float*)d_in[13];
    float* out = (float*)d_out;

    size_t o = 0;
    auto alloc = [&](size_t bytes) {
        void* p = (char*)d_ws + o;
        o += (bytes + 255) & ~(size_t)255;
        return p;
    };
    int* deg       = (int*)alloc((size_t)N_NODES * 4);
    int* offsets   = (int*)alloc((size_t)(N_NODES + 1) * 4);
    int* cursor    = (int*)alloc((size_t)N_NODES * 4);
    int* incl      = (int*)alloc((size_t)N_NODES * 4);
    int* blocksums = (int*)alloc((size_t)SCAN_BLOCKS * 4);
    int* blockoff  = (int*)alloc(256 * 4);
    int* csr_src   = (int*)alloc((size_t)N_EDGES * 4);
    float* pooled  = (float*)alloc(HIDDEN * 4);
    ushort* Wt1    = (ushort*)alloc((size_t)HIDDEN * NODE_DIM * 2);   // 64 KB
    ushort* Wt2    = (ushort*)alloc((size_t)HIDDEN * HIDDEN * 2);     // 128 KB
    ushort* nf_bf  = (ushort*)alloc((size_t)N_NODES * NODE_DIM * 2);  // 12.8 MB
    ushort* agg1   = (ushort*)alloc((size_t)N_NODES * NODE_DIM * 2);  // 12.8 MB
    ushort* x1     = (ushort*)alloc((size_t)N_NODES * HIDDEN * 2);    // 25.6 MB
    ushort* agg2   = (ushort*)alloc((size_t)N_NODES * HIDDEN * 2);    // 25.6 MB

    hipMemsetAsync(deg, 0, (size_t)N_NODES * 4, stream);
    hipMemsetAsync(pooled, 0, HIDDEN * 4, stream);

    prep_kernel<<<(NF4 + NODE_DIM * HIDDEN + HIDDEN * HIDDEN) / 256, 256, 0, stream>>>(
        node_features, W1, W2, nf_bf, Wt1, Wt2);

    hist_kernel<<<N_EDGES / 256, 256, 0, stream>>>(dst, deg);
    scan_a_kernel<<<SCAN_BLOCKS, 256, 0, stream>>>(deg, incl, blocksums);
    scan_b_kernel<<<1, 256, 0, stream>>>(blocksums, blockoff);
    scan_c_kernel<<<SCAN_BLOCKS, 256, 0, stream>>>(deg, incl, blockoff, offsets, cursor);
    scatter_kernel<<<N_EDGES / 256, 256, 0, stream>>>(src, dst, cursor, csr_src);

    const int GEMM_GRID = (N_NODES + 63) / 64;  // 782

    // layer 1
    agg_kernel<NODE_DIM><<<N_NODES * 16 / 256, 256, 0, stream>>>(nf_bf, offsets, csr_src, agg1);
    gemm_mfma_kernel<NODE_DIM, false><<<GEMM_GRID, 256, 0, stream>>>(agg1, Wt1, b1, x1, nullptr);

    // layer 2 (+ fused mean-pool)
    agg_kernel<HIDDEN><<<N_NODES * 16 / 256, 256, 0, stream>>>(x1, offsets, csr_src, agg2);
    gemm_mfma_kernel<HIDDEN, true><<<GEMM_GRID, 256, 0, stream>>>(agg2, Wt2, b2, nullptr, pooled);

    head_kernel<<<1, 256, 0, stream>>>(pooled, conditions, Wfc, bfc,
                                       Wmean, bmean, Wlogvar, blogvar, out);
}

// Round 5
// 299.503 us; speedup vs baseline: 2.2651x; 1.0293x over previous
//
#include <hip/hip_runtime.h>

#define N_NODES   50000
#define N_EDGES   800000
#define NODE_DIM  128
#define HIDDEN    256
#define LATENT    128
#define COND      5

#define SCAN_BLOCKS ((N_NODES + 255) / 256)   // 196

typedef unsigned int uint;
typedef unsigned short ushort;

typedef __attribute__((ext_vector_type(8))) short bf16x8;
typedef __attribute__((ext_vector_type(4))) float f32x4;

static __device__ __forceinline__ ushort f32_to_bf16(float f) {
    union { float f; uint u; } v; v.f = f;
    uint r = v.u + 0x7FFF + ((v.u >> 16) & 1);   // RNE
    return (ushort)(r >> 16);
}
static __device__ __forceinline__ float bf16_to_f32(uint h) {
    union { uint u; float f; } v; v.u = h << 16;
    return v.f;
}
static __device__ __forceinline__ uint pack_bf16(float lo, float hi) {
    return (uint)f32_to_bf16(lo) | ((uint)f32_to_bf16(hi) << 16);
}

// ---------------- prep: nf -> bf16, W transpose, deg zero (fused) ----------------

#define NF4   (N_NODES * NODE_DIM / 4)            // 1,600,000
#define PREP1 (NF4 + NODE_DIM * HIDDEN)           // + 32768
#define PREP2 (PREP1 + HIDDEN * HIDDEN)           // + 65536
#define PREP3 (PREP2 + N_NODES)                   // + 50000 (deg zero)

__global__ void prep_kernel(const float* __restrict__ nf,
                            const float* __restrict__ W1, const float* __restrict__ W2,
                            ushort* __restrict__ nf_bf,
                            ushort* __restrict__ Wt1, ushort* __restrict__ Wt2,
                            int* __restrict__ deg) {
    int id = blockIdx.x * blockDim.x + threadIdx.x;
    if (id < NF4) {
        float4 v = reinterpret_cast<const float4*>(nf)[id];
        ushort4 o;
        o.x = f32_to_bf16(v.x); o.y = f32_to_bf16(v.y);
        o.z = f32_to_bf16(v.z); o.w = f32_to_bf16(v.w);
        reinterpret_cast<ushort4*>(nf_bf)[id] = o;
    } else if (id < PREP1) {                       // W1 [128,256] -> Wt1 [256,128]
        int i = id - NF4;
        int k = i >> 8, c = i & 255;
        Wt1[c * NODE_DIM + k] = f32_to_bf16(W1[i]);
    } else if (id < PREP2) {                       // W2 [256,256] -> Wt2 [256,256]
        int i = id - PREP1;
        int k = i >> 8, c = i & 255;
        Wt2[c * HIDDEN + k] = f32_to_bf16(W2[i]);
    } else if (id < PREP3) {
        deg[id - PREP2] = 0;
    }
}

// ---------------- CSR build ----------------

__global__ void hist_kernel(const int* __restrict__ dst, int* __restrict__ deg) {
    int e = blockIdx.x * blockDim.x + threadIdx.x;
    if (e < N_EDGES) atomicAdd(&deg[dst[e]], 1);
}

// phase A: per-block inclusive scan (256 elems/block) + block totals
__global__ void scan_a_kernel(const int* __restrict__ deg, int* __restrict__ incl,
                              int* __restrict__ blocksums) {
    int i = blockIdx.x * 256 + threadIdx.x;
    int lane = threadIdx.x & 63;
    int w    = threadIdx.x >> 6;
    int v = (i < N_NODES) ? deg[i] : 0;
    int s = v;
#pragma unroll
    for (int d = 1; d < 64; d <<= 1) {
        int t = __shfl_up(s, d);
        if (lane >= d) s += t;
    }
    __shared__ int wsum[4];
    if (lane == 63) wsum[w] = s;
    __syncthreads();
    int add = 0;
    for (int k = 0; k < w; ++k) add += wsum[k];
    s += add;
    if (i < N_NODES) incl[i] = s;
    if (threadIdx.x == 255) blocksums[blockIdx.x] = s;
}

// phase B: single block scans the 196 block totals (exclusive); also zeroes pooled
__global__ void scan_b_kernel(const int* __restrict__ blocksums, int* __restrict__ blockoff,
                              float* __restrict__ pooled) {
    __shared__ int s[256];
    int t = threadIdx.x;
    pooled[t] = 0.f;
    s[t] = (t < SCAN_BLOCKS) ? blocksums[t] : 0;
    __syncthreads();
    for (int off = 1; off < 256; off <<= 1) {
        int v = (t >= off) ? s[t - off] : 0;
        __syncthreads();
        s[t] += v;
        __syncthreads();
    }
    blockoff[t] = (t == 0) ? 0 : s[t - 1];
}

// phase C: offsets/cursor = blockoff + incl - deg
__global__ void scan_c_kernel(const int* __restrict__ deg, const int* __restrict__ incl,
                              const int* __restrict__ blockoff,
                              int* __restrict__ offsets, int* __restrict__ cursor) {
    int i = blockIdx.x * 256 + threadIdx.x;
    if (i < N_NODES) {
        int inc = incl[i];
        int off = blockoff[blockIdx.x] + inc - deg[i];
        offsets[i] = off;
        cursor[i]  = off;
        if (i == N_NODES - 1) offsets[N_NODES] = blockoff[blockIdx.x] + inc;
    }
}

__global__ void scatter_kernel(const int* __restrict__ src, const int* __restrict__ dst,
                               int* __restrict__ cursor, int* __restrict__ csr_src) {
    int e = blockIdx.x * blockDim.x + threadIdx.x;
    if (e < N_EDGES) {
        int pos = atomicAdd(&cursor[dst[e]], 1);
        csr_src[pos] = src[e];
    }
}

// ---------------- aggregation v2: 16-lane group per node, pipelined 8-edge buffers ----------------
// Lane gl handles NH contiguous 16B half-row slices: elements [h*128 + gl*8, +8).
// 8-edge register buffer (static indices) -> 8*NH independent loads in flight.

template <int D>
__global__ __launch_bounds__(256, 4) void agg_kernel(const ushort* __restrict__ x,
                                                     const int* __restrict__ offsets,
                                                     const int* __restrict__ csr_src,
                                                     ushort* __restrict__ out) {
    constexpr int NH = D / 128;        // uint4 half-rows per lane: 1 (D=128) or 2 (D=256)
    int tid   = blockIdx.x * blockDim.x + threadIdx.x;
    int node  = tid >> 4;
    int gl    = threadIdx.x & 15;
    int lane  = threadIdx.x & 63;
    int gbase = lane & 48;
    if (node >= N_NODES) return;
    int j0 = offsets[node], j1 = offsets[node + 1];

    float acc[NH][8];
#pragma unroll
    for (int h = 0; h < NH; ++h)
#pragma unroll
        for (int i = 0; i < 8; ++i) acc[h][i] = 0.f;

    auto consume = [&](uint4 u, int h) {
        acc[h][0] += bf16_to_f32(u.x & 0xFFFFu); acc[h][1] += bf16_to_f32(u.x >> 16);
        acc[h][2] += bf16_to_f32(u.y & 0xFFFFu); acc[h][3] += bf16_to_f32(u.y >> 16);
        acc[h][4] += bf16_to_f32(u.z & 0xFFFFu); acc[h][5] += bf16_to_f32(u.z >> 16);
        acc[h][6] += bf16_to_f32(u.w & 0xFFFFu); acc[h][7] += bf16_to_f32(u.w >> 16);
    };

    // prefetched 16-edge index window
    int idx = (j0 + gl < j1) ? csr_src[j0 + gl] : -1;

    for (int jb = j0; jb < j1; jb += 16) {
        int idx_next = (jb + 16 + gl < j1) ? csr_src[jb + 16 + gl] : -1;
        int nrem = j1 - jb;
        if (nrem >= 16) {
#pragma unroll
            for (int half = 0; half < 2; ++half) {
                uint4 b[8 * NH];
#pragma unroll
                for (int i = 0; i < 8; ++i) {
                    int s = __shfl(idx, gbase + half * 8 + i);
                    const ushort* row = x + (size_t)s * D + gl * 8;
#pragma unroll
                    for (int h = 0; h < NH; ++h)
                        b[i * NH + h] = *reinterpret_cast<const uint4*>(row + h * 128);
                }
#pragma unroll
                for (int i = 0; i < 8; ++i)
#pragma unroll
                    for (int h = 0; h < NH; ++h)
                        consume(b[i * NH + h], h);
            }
        } else {
            for (int i = 0; i < nrem; ++i) {
                int s = __shfl(idx, gbase + i);
                const ushort* row = x + (size_t)s * D + gl * 8;
#pragma unroll
                for (int h = 0; h < NH; ++h)
                    consume(*reinterpret_cast<const uint4*>(row + h * 128), h);
            }
        }
        idx = idx_next;
    }

    ushort* orow = out + (size_t)node * D + gl * 8;
#pragma unroll
    for (int h = 0; h < NH; ++h) {
        uint4 o;
        o.x = pack_bf16(acc[h][0], acc[h][1]);
        o.y = pack_bf16(acc[h][2], acc[h][3]);
        o.z = pack_bf16(acc[h][4], acc[h][5]);
        o.w = pack_bf16(acc[h][6], acc[h][7]);
        *reinterpret_cast<uint4*>(orow + h * 128) = o;
    }
}

// ---------------- MFMA GEMM: X = relu(A[M,K]bf16 @ W[K,256] + b), LDS-free ----------------

template <int K, bool POOL>
__global__ __launch_bounds__(256) void gemm_mfma_kernel(const ushort* __restrict__ A,
                                                        const ushort* __restrict__ Wt,
                                                        const float* __restrict__ bias,
                                                        ushort* __restrict__ Xout,
                                                        float* __restrict__ pooled) {
    const int lane = threadIdx.x & 63;
    const int wv   = threadIdx.x >> 6;       // 0..3
    const int row0 = blockIdx.x * 64;
    const int col0 = wv * 64;
    const int fr   = lane & 15;              // fragment row (A) / col (B)
    const int kg   = (lane >> 4) * 8;        // fragment k-offset

    const bf16x8 zero8 = {0, 0, 0, 0, 0, 0, 0, 0};
    f32x4 acc[4][4];
#pragma unroll
    for (int rt = 0; rt < 4; ++rt)
#pragma unroll
        for (int ct = 0; ct < 4; ++ct)
            acc[rt][ct] = (f32x4){0.f, 0.f, 0.f, 0.f};

#pragma unroll
    for (int k0 = 0; k0 < K; k0 += 32) {
        bf16x8 af[4], bfv[4];
#pragma unroll
        for (int rt = 0; rt < 4; ++rt) {
            int r = row0 + rt * 16 + fr;
            af[rt] = (r < N_NODES)
                   ? *reinterpret_cast<const bf16x8*>(A + (size_t)r * K + k0 + kg)
                   : zero8;
        }
#pragma unroll
        for (int ct = 0; ct < 4; ++ct) {
            int c = col0 + ct * 16 + fr;
            bfv[ct] = *reinterpret_cast<const bf16x8*>(Wt + (size_t)c * K + k0 + kg);
        }
#pragma unroll
        for (int rt = 0; rt < 4; ++rt)
#pragma unroll
            for (int ct = 0; ct < 4; ++ct)
                acc[rt][ct] = __builtin_amdgcn_mfma_f32_16x16x32_bf16(af[rt], bfv[ct], acc[rt][ct], 0, 0, 0);
    }

    float bcol[4];
#pragma unroll
    for (int ct = 0; ct < 4; ++ct) bcol[ct] = bias[col0 + ct * 16 + fr];

    const int mrow = (lane >> 4) * 4;

    if constexpr (POOL) {
        float cs[4] = {0.f, 0.f, 0.f, 0.f};
#pragma unroll
        for (int rt = 0; rt < 4; ++rt) {
#pragma unroll
            for (int e = 0; e < 4; ++e) {
                int m = row0 + rt * 16 + mrow + e;
                if (m < N_NODES) {
#pragma unroll
                    for (int ct = 0; ct < 4; ++ct)
                        cs[ct] += fmaxf(acc[rt][ct][e] + bcol[ct], 0.f);
                }
            }
        }
#pragma unroll
        for (int ct = 0; ct < 4; ++ct) {
            cs[ct] += __shfl_xor(cs[ct], 16);
            cs[ct] += __shfl_xor(cs[ct], 32);
        }
        if (lane < 16) {
#pragma unroll
            for (int ct = 0; ct < 4; ++ct)
                atomicAdd(&pooled[col0 + ct * 16 + lane], cs[ct]);
        }
    } else {
#pragma unroll
        for (int rt = 0; rt < 4; ++rt) {
#pragma unroll
            for (int e = 0; e < 4; ++e) {
                int m = row0 + rt * 16 + mrow + e;
                if (m < N_NODES) {
#pragma unroll
                    for (int ct = 0; ct < 4; ++ct) {
                        float v = fmaxf(acc[rt][ct][e] + bcol[ct], 0.f);
                        Xout[(size_t)m * HIDDEN + col0 + ct * 16 + fr] = f32_to_bf16(v);
                    }
                }
            }
        }
    }
}

// ---------------- head MLP ----------------

__global__ void head_kernel(const float* __restrict__ pooled_sum, const float* __restrict__ cond,
                            const float* __restrict__ Wfc, const float* __restrict__ bfc,
                            const float* __restrict__ Wmean, const float* __restrict__ bmean,
                            const float* __restrict__ Wlogvar, const float* __restrict__ blogvar,
                            float* __restrict__ out) {
    __shared__ float v[HIDDEN + COND];
    __shared__ float h[LATENT];
    int t = threadIdx.x;
    if (t < HIDDEN) v[t] = pooled_sum[t] * (1.0f / N_NODES);
    if (t < COND) v[HIDDEN + t] = cond[t];
    __syncthreads();
    if (t < LATENT) {
        float s = bfc[t];
        for (int k = 0; k < HIDDEN + COND; ++k) s += v[k] * Wfc[k * LATENT + t];
        h[t] = fmaxf(s, 0.f);
    }
    __syncthreads();
    if (t < LATENT) {
        float s = bmean[t];
        for (int k = 0; k < LATENT; ++k) s += h[k] * Wmean[k * LATENT + t];
        out[t] = s;
    } else {
        int j = t - LATENT;
        float s = blogvar[j];
        for (int k = 0; k < LATENT; ++k) s += h[k] * Wlogvar[k * LATENT + j];
        out[LATENT + j] = s;
    }
}

// ---------------- launch ----------------

extern "C" void kernel_launch(void* const* d_in, const int* in_sizes, int n_in,
                              void* d_out, int out_size, void* d_ws, size_t ws_size,
                              hipStream_t stream) {
    const float* node_features = (const float*)d_in[0];
    const float* conditions    = (const float*)d_in[1];
    const int*   src           = (const int*)d_in[2];
    const int*   dst           = (const int*)d_in[3];
    const float* W1  = (const float*)d_in[4];
    const float* b1  = (const float*)d_in[5];
    const float* W2  = (const float*)d_in[6];
    const float* b2  = (const float*)d_in[7];
    const float* Wfc = (const float*)d_in[8];
    const float* bfc = (const float*)d_in[9];
    const float* Wmean   = (const float*)d_in[10];
    const float* bmean   = (const float*)d_in[11];
    const float* Wlogvar = (const float*)d_in[12];
    const float* blogvar = (const float*)d_in[13];
    float* out = (float*)d_out;

    size_t o = 0;
    auto alloc = [&](size_t bytes) {
        void* p = (char*)d_ws + o;
        o += (bytes + 255) & ~(size_t)255;
        return p;
    };
    int* deg       = (int*)alloc((size_t)N_NODES * 4);
    int* offsets   = (int*)alloc((size_t)(N_NODES + 1) * 4);
    int* cursor    = (int*)alloc((size_t)N_NODES * 4);
    int* incl      = (int*)alloc((size_t)N_NODES * 4);
    int* blocksums = (int*)alloc((size_t)SCAN_BLOCKS * 4);
    int* blockoff  = (int*)alloc(256 * 4);
    int* csr_src   = (int*)alloc((size_t)N_EDGES * 4);
    float* pooled  = (float*)alloc(HIDDEN * 4);
    ushort* Wt1    = (ushort*)alloc((size_t)HIDDEN * NODE_DIM * 2);   // 64 KB
    ushort* Wt2    = (ushort*)alloc((size_t)HIDDEN * HIDDEN * 2);     // 128 KB
    ushort* nf_bf  = (ushort*)alloc((size_t)N_NODES * NODE_DIM * 2);  // 12.8 MB
    ushort* agg1   = (ushort*)alloc((size_t)N_NODES * NODE_DIM * 2);  // 12.8 MB
    ushort* x1     = (ushort*)alloc((size_t)N_NODES * HIDDEN * 2);    // 25.6 MB
    ushort* agg2   = (ushort*)alloc((size_t)N_NODES * HIDDEN * 2);    // 25.6 MB

    prep_kernel<<<(PREP3 + 255) / 256, 256, 0, stream>>>(
        node_features, W1, W2, nf_bf, Wt1, Wt2, deg);

    hist_kernel<<<N_EDGES / 256, 256, 0, stream>>>(dst, deg);
    scan_a_kernel<<<SCAN_BLOCKS, 256, 0, stream>>>(deg, incl, blocksums);
    scan_b_kernel<<<1, 256, 0, stream>>>(blocksums, blockoff, pooled);
    scan_c_kernel<<<SCAN_BLOCKS, 256, 0, stream>>>(deg, incl, blockoff, offsets, cursor);
    scatter_kernel<<<N_EDGES / 256, 256, 0, stream>>>(src, dst, cursor, csr_src);

    const int GEMM_GRID = (N_NODES + 63) / 64;  // 782

    // layer 1
    agg_kernel<NODE_DIM><<<N_NODES * 16 / 256, 256, 0, stream>>>(nf_bf, offsets, csr_src, agg1);
    gemm_mfma_kernel<NODE_DIM, false><<<GEMM_GRID, 256, 0, stream>>>(agg1, Wt1, b1, x1, nullptr);

    // layer 2 (+ fused mean-pool)
    agg_kernel<HIDDEN><<<N_NODES * 16 / 256, 256, 0, stream>>>(x1, offsets, csr_src, agg2);
    gemm_mfma_kernel<HIDDEN, true><<<GEMM_GRID, 256, 0, stream>>>(agg2, Wt2, b2, nullptr, pooled);

    head_kernel<<<1, 256, 0, stream>>>(pooled, conditions, Wfc, bfc,
                                       Wmean, bmean, Wlogvar, blogvar, out);
}

// Round 6
// 280.986 us; speedup vs baseline: 2.4144x; 1.0659x over previous
//
#include <hip/hip_runtime.h>

#define N_NODES   50000
#define N_EDGES   800000
#define NODE_DIM  128
#define HIDDEN    256
#define LATENT    128
#define COND      5

#define SCAN_BLOCKS ((N_NODES + 255) / 256)   // 196

typedef unsigned int uint;
typedef unsigned short ushort;

typedef __attribute__((ext_vector_type(8))) short bf16x8;
typedef __attribute__((ext_vector_type(4))) float f32x4;

static __device__ __forceinline__ ushort f32_to_bf16(float f) {
    union { float f; uint u; } v; v.f = f;
    uint r = v.u + 0x7FFF + ((v.u >> 16) & 1);   // RNE
    return (ushort)(r >> 16);
}
static __device__ __forceinline__ float bf16_to_f32(uint h) {
    union { uint u; float f; } v; v.u = h << 16;
    return v.f;
}
static __device__ __forceinline__ uint pack_bf16(float lo, float hi) {
    return (uint)f32_to_bf16(lo) | ((uint)f32_to_bf16(hi) << 16);
}

// ---------------- prep: nf -> bf16, W transpose, deg zero, pooled zero ----------------

#define NF4   (N_NODES * NODE_DIM / 4)            // 1,600,000
#define PREP1 (NF4 + NODE_DIM * HIDDEN)           // + 32768
#define PREP2 (PREP1 + HIDDEN * HIDDEN)           // + 65536
#define PREP3 (PREP2 + N_NODES)                   // + 50000 (deg zero)
#define PREP4 (PREP3 + HIDDEN)                    // + 256 (pooled zero)

__global__ void prep_kernel(const float* __restrict__ nf,
                            const float* __restrict__ W1, const float* __restrict__ W2,
                            ushort* __restrict__ nf_bf,
                            ushort* __restrict__ Wt1, ushort* __restrict__ Wt2,
                            int* __restrict__ deg, float* __restrict__ pooled) {
    int id = blockIdx.x * blockDim.x + threadIdx.x;
    if (id < NF4) {
        float4 v = reinterpret_cast<const float4*>(nf)[id];
        ushort4 o;
        o.x = f32_to_bf16(v.x); o.y = f32_to_bf16(v.y);
        o.z = f32_to_bf16(v.z); o.w = f32_to_bf16(v.w);
        reinterpret_cast<ushort4*>(nf_bf)[id] = o;
    } else if (id < PREP1) {                       // W1 [128,256] -> Wt1 [256,128]
        int i = id - NF4;
        int k = i >> 8, c = i & 255;
        Wt1[c * NODE_DIM + k] = f32_to_bf16(W1[i]);
    } else if (id < PREP2) {                       // W2 [256,256] -> Wt2 [256,256]
        int i = id - PREP1;
        int k = i >> 8, c = i & 255;
        Wt2[c * HIDDEN + k] = f32_to_bf16(W2[i]);
    } else if (id < PREP3) {
        deg[id - PREP2] = 0;
    } else if (id < PREP4) {
        pooled[id - PREP3] = 0.f;
    }
}

// ---------------- CSR build ----------------

__global__ void hist_kernel(const int* __restrict__ dst, int* __restrict__ deg) {
    int e = blockIdx.x * blockDim.x + threadIdx.x;
    if (e < N_EDGES) atomicAdd(&deg[dst[e]], 1);
}

// phase A: per-block inclusive scan (256 elems/block) + block totals
__global__ void scan_a_kernel(const int* __restrict__ deg, int* __restrict__ incl,
                              int* __restrict__ blocksums) {
    int i = blockIdx.x * 256 + threadIdx.x;
    int lane = threadIdx.x & 63;
    int w    = threadIdx.x >> 6;
    int v = (i < N_NODES) ? deg[i] : 0;
    int s = v;
#pragma unroll
    for (int d = 1; d < 64; d <<= 1) {
        int t = __shfl_up(s, d);
        if (lane >= d) s += t;
    }
    __shared__ int wsum[4];
    if (lane == 63) wsum[w] = s;
    __syncthreads();
    int add = 0;
    for (int k = 0; k < w; ++k) add += wsum[k];
    s += add;
    if (i < N_NODES) incl[i] = s;
    if (threadIdx.x == 255) blocksums[blockIdx.x] = s;
}

// phase C: every block redundantly scans the 196 block totals in LDS, then
// offsets/cursor = blockoff + incl - deg   (scan_b eliminated)
__global__ void scan_c_kernel(const int* __restrict__ deg, const int* __restrict__ incl,
                              const int* __restrict__ blocksums,
                              int* __restrict__ offsets, int* __restrict__ cursor) {
    __shared__ int s[256];
    int t = threadIdx.x;
    s[t] = (t < SCAN_BLOCKS) ? blocksums[t] : 0;
    __syncthreads();
    for (int off = 1; off < 256; off <<= 1) {
        int v = (t >= off) ? s[t - off] : 0;
        __syncthreads();
        s[t] += v;
        __syncthreads();
    }
    int bo = (blockIdx.x == 0) ? 0 : s[blockIdx.x - 1];
    int i = blockIdx.x * 256 + t;
    if (i < N_NODES) {
        int inc = incl[i];
        int off = bo + inc - deg[i];
        offsets[i] = off;
        cursor[i]  = off;
        if (i == N_NODES - 1) offsets[N_NODES] = bo + inc;
    }
}

__global__ void scatter_kernel(const int* __restrict__ src, const int* __restrict__ dst,
                               int* __restrict__ cursor, int* __restrict__ csr_src) {
    int e = blockIdx.x * blockDim.x + threadIdx.x;
    if (e < N_EDGES) {
        int pos = atomicAdd(&cursor[dst[e]], 1);
        csr_src[pos] = src[e];
    }
}

// ---------------- fused: gather-aggregate 32 nodes -> LDS -> MFMA GEMM -> relu -> out ----------------
// Xin [N,K] bf16 gather source; Wt [256,K] bf16 (=W^T); out = relu(agg @ W + b).
// POOL=true: column-sum into pooled[256] (x2 never stored). POOL=false: store bf16 [N,256].
// Phase 1: 16 groups of 16 lanes, each group aggregates 2 nodes (fp32 accum) -> LDS bf16.
// Phase 2: 4 waves, each 32 rows x 64 cols via 2x4 fragments of mfma_f32_16x16x32_bf16.

template <int K, bool POOL>
__global__ __launch_bounds__(256, 4) void fused_kernel(const ushort* __restrict__ Xin,
                                                       const int* __restrict__ offsets,
                                                       const int* __restrict__ csr_src,
                                                       const ushort* __restrict__ Wt,
                                                       const float* __restrict__ bias,
                                                       ushort* __restrict__ Xout,
                                                       float* __restrict__ pooled) {
    constexpr int NH = K / 128;            // 16B-slices per lane per row: 1 or 2
    constexpr int STRIDE = K + 8;          // +8 bf16 = +16B pad: 2-way banks, 16B-aligned
    __shared__ ushort As[32][STRIDE];

    const int t     = threadIdx.x;
    const int lane  = t & 63;
    const int gl    = lane & 15;
    const int gid   = t >> 4;              // 0..15
    const int gbase = lane & 48;
    const int row0  = blockIdx.x * 32;

    // ---- phase 1: gather-aggregate ----
    for (int q = 0; q < 2; ++q) {
        const int nl   = gid * 2 + q;
        const int node = row0 + nl;
        float acc[NH][8];
#pragma unroll
        for (int h = 0; h < NH; ++h)
#pragma unroll
            for (int i = 0; i < 8; ++i) acc[h][i] = 0.f;

        if (node < N_NODES) {
            const int j0 = offsets[node], j1 = offsets[node + 1];
            int idx = (j0 + gl < j1) ? csr_src[j0 + gl] : -1;
            for (int jb = j0; jb < j1; jb += 16) {
                int idx_next = (jb + 16 + gl < j1) ? csr_src[jb + 16 + gl] : -1;
                int nrem = j1 - jb;
                if (nrem >= 16) {
#pragma unroll
                    for (int half = 0; half < 2; ++half) {
                        uint4 b[8 * NH];
#pragma unroll
                        for (int i = 0; i < 8; ++i) {
                            int s = __shfl(idx, gbase + half * 8 + i);
                            const ushort* row = Xin + (size_t)s * K + gl * 8;
#pragma unroll
                            for (int h = 0; h < NH; ++h)
                                b[i * NH + h] = *reinterpret_cast<const uint4*>(row + h * 128);
                        }
#pragma unroll
                        for (int i = 0; i < 8; ++i) {
#pragma unroll
                            for (int h = 0; h < NH; ++h) {
                                uint4 u = b[i * NH + h];
                                acc[h][0] += bf16_to_f32(u.x & 0xFFFFu); acc[h][1] += bf16_to_f32(u.x >> 16);
                                acc[h][2] += bf16_to_f32(u.y & 0xFFFFu); acc[h][3] += bf16_to_f32(u.y >> 16);
                                acc[h][4] += bf16_to_f32(u.z & 0xFFFFu); acc[h][5] += bf16_to_f32(u.z >> 16);
                                acc[h][6] += bf16_to_f32(u.w & 0xFFFFu); acc[h][7] += bf16_to_f32(u.w >> 16);
                            }
                        }
                    }
                } else {
                    for (int i = 0; i < nrem; ++i) {
                        int s = __shfl(idx, gbase + i);
                        const ushort* row = Xin + (size_t)s * K + gl * 8;
#pragma unroll
                        for (int h = 0; h < NH; ++h) {
                            uint4 u = *reinterpret_cast<const uint4*>(row + h * 128);
                            acc[h][0] += bf16_to_f32(u.x & 0xFFFFu); acc[h][1] += bf16_to_f32(u.x >> 16);
                            acc[h][2] += bf16_to_f32(u.y & 0xFFFFu); acc[h][3] += bf16_to_f32(u.y >> 16);
                            acc[h][4] += bf16_to_f32(u.z & 0xFFFFu); acc[h][5] += bf16_to_f32(u.z >> 16);
                            acc[h][6] += bf16_to_f32(u.w & 0xFFFFu); acc[h][7] += bf16_to_f32(u.w >> 16);
                        }
                    }
                }
                idx = idx_next;
            }
        }
        ushort* orow = &As[nl][gl * 8];
#pragma unroll
        for (int h = 0; h < NH; ++h) {
            uint4 o2;
            o2.x = pack_bf16(acc[h][0], acc[h][1]);
            o2.y = pack_bf16(acc[h][2], acc[h][3]);
            o2.z = pack_bf16(acc[h][4], acc[h][5]);
            o2.w = pack_bf16(acc[h][6], acc[h][7]);
            *reinterpret_cast<uint4*>(orow + h * 128) = o2;
        }
    }
    __syncthreads();

    // ---- phase 2: MFMA 32x256 ----
    const int wv   = t >> 6;               // 0..3
    const int col0 = wv * 64;
    const int fr   = lane & 15;
    const int kg   = (lane >> 4) * 8;

    f32x4 acc2[2][4];
#pragma unroll
    for (int rt = 0; rt < 2; ++rt)
#pragma unroll
        for (int ct = 0; ct < 4; ++ct)
            acc2[rt][ct] = (f32x4){0.f, 0.f, 0.f, 0.f};

#pragma unroll
    for (int k0 = 0; k0 < K; k0 += 32) {
        bf16x8 af[2], bfv[4];
#pragma unroll
        for (int rt = 0; rt < 2; ++rt)
            af[rt] = *reinterpret_cast<const bf16x8*>(&As[rt * 16 + fr][k0 + kg]);
#pragma unroll
        for (int ct = 0; ct < 4; ++ct)
            bfv[ct] = *reinterpret_cast<const bf16x8*>(Wt + (size_t)(col0 + ct * 16 + fr) * K + k0 + kg);
#pragma unroll
        for (int rt = 0; rt < 2; ++rt)
#pragma unroll
            for (int ct = 0; ct < 4; ++ct)
                acc2[rt][ct] = __builtin_amdgcn_mfma_f32_16x16x32_bf16(af[rt], bfv[ct], acc2[rt][ct], 0, 0, 0);
    }

    float bcol[4];
#pragma unroll
    for (int ct = 0; ct < 4; ++ct) bcol[ct] = bias[col0 + ct * 16 + fr];

    const int mrow = (lane >> 4) * 4;

    if constexpr (POOL) {
        float cs[4] = {0.f, 0.f, 0.f, 0.f};
#pragma unroll
        for (int rt = 0; rt < 2; ++rt) {
#pragma unroll
            for (int e = 0; e < 4; ++e) {
                int m = row0 + rt * 16 + mrow + e;
                if (m < N_NODES) {
#pragma unroll
                    for (int ct = 0; ct < 4; ++ct)
                        cs[ct] += fmaxf(acc2[rt][ct][e] + bcol[ct], 0.f);
                }
            }
        }
#pragma unroll
        for (int ct = 0; ct < 4; ++ct) {
            cs[ct] += __shfl_xor(cs[ct], 16);
            cs[ct] += __shfl_xor(cs[ct], 32);
        }
        if (lane < 16) {
#pragma unroll
            for (int ct = 0; ct < 4; ++ct)
                atomicAdd(&pooled[col0 + ct * 16 + lane], cs[ct]);
        }
    } else {
#pragma unroll
        for (int rt = 0; rt < 2; ++rt) {
#pragma unroll
            for (int e = 0; e < 4; ++e) {
                int m = row0 + rt * 16 + mrow + e;
                if (m < N_NODES) {
#pragma unroll
                    for (int ct = 0; ct < 4; ++ct) {
                        float v = fmaxf(acc2[rt][ct][e] + bcol[ct], 0.f);
                        Xout[(size_t)m * HIDDEN + col0 + ct * 16 + fr] = f32_to_bf16(v);
                    }
                }
            }
        }
    }
}

// ---------------- head MLP ----------------

__global__ void head_kernel(const float* __restrict__ pooled_sum, const float* __restrict__ cond,
                            const float* __restrict__ Wfc, const float* __restrict__ bfc,
                            const float* __restrict__ Wmean, const float* __restrict__ bmean,
                            const float* __restrict__ Wlogvar, const float* __restrict__ blogvar,
                            float* __restrict__ out) {
    __shared__ float v[HIDDEN + COND];
    __shared__ float h[LATENT];
    int t = threadIdx.x;
    if (t < HIDDEN) v[t] = pooled_sum[t] * (1.0f / N_NODES);
    if (t < COND) v[HIDDEN + t] = cond[t];
    __syncthreads();
    if (t < LATENT) {
        float s = bfc[t];
        for (int k = 0; k < HIDDEN + COND; ++k) s += v[k] * Wfc[k * LATENT + t];
        h[t] = fmaxf(s, 0.f);
    }
    __syncthreads();
    if (t < LATENT) {
        float s = bmean[t];
        for (int k = 0; k < LATENT; ++k) s += h[k] * Wmean[k * LATENT + t];
        out[t] = s;
    } else {
        int j = t - LATENT;
        float s = blogvar[j];
        for (int k = 0; k < LATENT; ++k) s += h[k] * Wlogvar[k * LATENT + j];
        out[LATENT + j] = s;
    }
}

// ---------------- launch ----------------

extern "C" void kernel_launch(void* const* d_in, const int* in_sizes, int n_in,
                              void* d_out, int out_size, void* d_ws, size_t ws_size,
                              hipStream_t stream) {
    const float* node_features = (const float*)d_in[0];
    const float* conditions    = (const float*)d_in[1];
    const int*   src           = (const int*)d_in[2];
    const int*   dst           = (const int*)d_in[3];
    const float* W1  = (const float*)d_in[4];
    const float* b1  = (const float*)d_in[5];
    const float* W2  = (const float*)d_in[6];
    const float* b2  = (const float*)d_in[7];
    const float* Wfc = (const float*)d_in[8];
    const float* bfc = (const float*)d_in[9];
    const float* Wmean   = (const float*)d_in[10];
    const float* bmean   = (const float*)d_in[11];
    const float* Wlogvar = (const float*)d_in[12];
    const float* blogvar = (const float*)d_in[13];
    float* out = (float*)d_out;

    size_t o = 0;
    auto alloc = [&](size_t bytes) {
        void* p = (char*)d_ws + o;
        o += (bytes + 255) & ~(size_t)255;
        return p;
    };
    int* deg       = (int*)alloc((size_t)N_NODES * 4);
    int* offsets   = (int*)alloc((size_t)(N_NODES + 1) * 4);
    int* cursor    = (int*)alloc((size_t)N_NODES * 4);
    int* incl      = (int*)alloc((size_t)N_NODES * 4);
    int* blocksums = (int*)alloc((size_t)SCAN_BLOCKS * 4);
    int* csr_src   = (int*)alloc((size_t)N_EDGES * 4);
    float* pooled  = (float*)alloc(HIDDEN * 4);
    ushort* Wt1    = (ushort*)alloc((size_t)HIDDEN * NODE_DIM * 2);   // 64 KB
    ushort* Wt2    = (ushort*)alloc((size_t)HIDDEN * HIDDEN * 2);     // 128 KB
    ushort* nf_bf  = (ushort*)alloc((size_t)N_NODES * NODE_DIM * 2);  // 12.8 MB
    ushort* x1     = (ushort*)alloc((size_t)N_NODES * HIDDEN * 2);    // 25.6 MB

    prep_kernel<<<(PREP4 + 255) / 256, 256, 0, stream>>>(
        node_features, W1, W2, nf_bf, Wt1, Wt2, deg, pooled);

    hist_kernel<<<N_EDGES / 256, 256, 0, stream>>>(dst, deg);
    scan_a_kernel<<<SCAN_BLOCKS, 256, 0, stream>>>(deg, incl, blocksums);
    scan_c_kernel<<<SCAN_BLOCKS, 256, 0, stream>>>(deg, incl, blocksums, offsets, cursor);
    scatter_kernel<<<N_EDGES / 256, 256, 0, stream>>>(src, dst, cursor, csr_src);

    const int FUSED_GRID = (N_NODES + 31) / 32;  // 1563

    // layer 1: gather(nf_bf) -> GEMM(W1) -> relu -> x1 (bf16)
    fused_kernel<NODE_DIM, false><<<FUSED_GRID, 256, 0, stream>>>(
        nf_bf, offsets, csr_src, Wt1, b1, x1, nullptr);

    // layer 2: gather(x1) -> GEMM(W2) -> relu -> column-sum into pooled
    fused_kernel<HIDDEN, true><<<FUSED_GRID, 256, 0, stream>>>(
        x1, offsets, csr_src, Wt2, b2, nullptr, pooled);

    head_kernel<<<1, 256, 0, stream>>>(pooled, conditions, Wfc, bfc,
                                       Wmean, bmean, Wlogvar, blogvar, out);
}

// Round 7
// 262.001 us; speedup vs baseline: 2.5893x; 1.0725x over previous
//
#include <hip/hip_runtime.h>

#define N_NODES   50000
#define N_EDGES   800000
#define NODE_DIM  128
#define HIDDEN    256
#define LATENT    128
#define COND      5

#define SCAN_BLOCKS ((N_NODES + 255) / 256)   // 196

typedef unsigned int uint;
typedef unsigned short ushort;
typedef unsigned char uchar;

typedef __attribute__((ext_vector_type(8))) short bf16x8;
typedef __attribute__((ext_vector_type(4))) float f32x4;

static __device__ __forceinline__ ushort f32_to_bf16(float f) {
    union { float f; uint u; } v; v.f = f;
    uint r = v.u + 0x7FFF + ((v.u >> 16) & 1);   // RNE
    return (ushort)(r >> 16);
}
static __device__ __forceinline__ uint pack_bf16(float lo, float hi) {
    return (uint)f32_to_bf16(lo) | ((uint)f32_to_bf16(hi) << 16);
}

// ---------------- fp8 e4m3 helpers (HW cvt with software fallback) ----------------

#if __has_builtin(__builtin_amdgcn_cvt_pk_f32_fp8) && __has_builtin(__builtin_amdgcn_cvt_pk_fp8_f32)
#define HW_FP8 1
#endif

#ifndef HW_FP8
static __device__ __forceinline__ float dec1_fp8(uint b) {
    uint sgn = b & 0x80, mag = b & 0x7f;
    float v;
    if (mag >= 8) {
        union { uint u; float f; } t;
        t.u = (((mag >> 3) + 120) << 23) | ((mag & 7) << 20);
        v = t.f;
    } else {
        v = (float)mag * 0.001953125f;   // 2^-9
    }
    return sgn ? -v : v;
}
static __device__ __forceinline__ uchar enc1_fp8(float f) {
    float a = fabsf(f);
    uint s = (f < 0.f) ? 0x80u : 0u;
    if (!(a >= 0.015625f)) {             // subnormal / zero
        int q = (int)(a * 512.f + 0.5f);
        if (q > 7) q = 7;
        return (uchar)(s | (uint)q);
    }
    if (a >= 448.f) return (uchar)(s | 0x7E);
    union { float f; uint u; } t; t.f = a;
    uint e = (t.u >> 23) - 120;          // e4m3 exponent field
    uint m = (t.u >> 20) & 7;
    uint rem = t.u & 0xFFFFF;
    uint v = (e << 3) | m;
    if (rem > 0x80000 || (rem == 0x80000 && (v & 1))) v++;
    if (v > 0x7E) v = 0x7E;
    return (uchar)(s | v);
}
#endif

static __device__ __forceinline__ void dec4_add(uint u, float* acc) {
#ifdef HW_FP8
    auto lo = __builtin_amdgcn_cvt_pk_f32_fp8((int)u, false);
    auto hi = __builtin_amdgcn_cvt_pk_f32_fp8((int)u, true);
    acc[0] += lo[0]; acc[1] += lo[1]; acc[2] += hi[0]; acc[3] += hi[1];
#else
    acc[0] += dec1_fp8(u & 0xff);
    acc[1] += dec1_fp8((u >> 8) & 0xff);
    acc[2] += dec1_fp8((u >> 16) & 0xff);
    acc[3] += dec1_fp8(u >> 24);
#endif
}
static __device__ __forceinline__ void dec2_add(uint u, float* acc) {
#ifdef HW_FP8
    auto lo = __builtin_amdgcn_cvt_pk_f32_fp8((int)u, false);
    acc[0] += lo[0]; acc[1] += lo[1];
#else
    acc[0] += dec1_fp8(u & 0xff);
    acc[1] += dec1_fp8((u >> 8) & 0xff);
#endif
}
static __device__ __forceinline__ uint enc2_fp8(float a, float b) {
#ifdef HW_FP8
    return (uint)__builtin_amdgcn_cvt_pk_fp8_f32(a, b, 0, false) & 0xFFFFu;
#else
    return (uint)enc1_fp8(a) | ((uint)enc1_fp8(b) << 8);
#endif
}
static __device__ __forceinline__ uchar enc1(float v) {
#ifdef HW_FP8
    return (uchar)(__builtin_amdgcn_cvt_pk_fp8_f32(v, v, 0, false) & 0xff);
#else
    return enc1_fp8(v);
#endif
}

// ---------------- prep: nf -> fp8, W transpose (bf16), deg/pooled zero ----------------

#define NF4   (N_NODES * NODE_DIM / 4)            // 1,600,000 (4 floats -> 4 bytes each)
#define PREP1 (NF4 + NODE_DIM * HIDDEN)           // + 32768
#define PREP2 (PREP1 + HIDDEN * HIDDEN)           // + 65536
#define PREP3 (PREP2 + N_NODES)                   // + 50000 (deg zero)
#define PREP4 (PREP3 + HIDDEN)                    // + 256 (pooled zero)

__global__ void prep_kernel(const float* __restrict__ nf,
                            const float* __restrict__ W1, const float* __restrict__ W2,
                            uchar* __restrict__ nf_fp8,
                            ushort* __restrict__ Wt1, ushort* __restrict__ Wt2,
                            int* __restrict__ deg, float* __restrict__ pooled) {
    int id = blockIdx.x * blockDim.x + threadIdx.x;
    if (id < NF4) {
        float4 v = reinterpret_cast<const float4*>(nf)[id];
        uint w = enc2_fp8(v.x, v.y) | (enc2_fp8(v.z, v.w) << 16);
        reinterpret_cast<uint*>(nf_fp8)[id] = w;
    } else if (id < PREP1) {                       // W1 [128,256] -> Wt1 [256,128]
        int i = id - NF4;
        int k = i >> 8, c = i & 255;
        Wt1[c * NODE_DIM + k] = f32_to_bf16(W1[i]);
    } else if (id < PREP2) {                       // W2 [256,256] -> Wt2 [256,256]
        int i = id - PREP1;
        int k = i >> 8, c = i & 255;
        Wt2[c * HIDDEN + k] = f32_to_bf16(W2[i]);
    } else if (id < PREP3) {
        deg[id - PREP2] = 0;
    } else if (id < PREP4) {
        pooled[id - PREP3] = 0.f;
    }
}

// ---------------- CSR build ----------------

__global__ void hist_kernel(const int* __restrict__ dst, int* __restrict__ deg) {
    int e = blockIdx.x * blockDim.x + threadIdx.x;
    if (e < N_EDGES) atomicAdd(&deg[dst[e]], 1);
}

__global__ void scan_a_kernel(const int* __restrict__ deg, int* __restrict__ incl,
                              int* __restrict__ blocksums) {
    int i = blockIdx.x * 256 + threadIdx.x;
    int lane = threadIdx.x & 63;
    int w    = threadIdx.x >> 6;
    int v = (i < N_NODES) ? deg[i] : 0;
    int s = v;
#pragma unroll
    for (int d = 1; d < 64; d <<= 1) {
        int t = __shfl_up(s, d);
        if (lane >= d) s += t;
    }
    __shared__ int wsum[4];
    if (lane == 63) wsum[w] = s;
    __syncthreads();
    int add = 0;
    for (int k = 0; k < w; ++k) add += wsum[k];
    s += add;
    if (i < N_NODES) incl[i] = s;
    if (threadIdx.x == 255) blocksums[blockIdx.x] = s;
}

__global__ void scan_c_kernel(const int* __restrict__ deg, const int* __restrict__ incl,
                              const int* __restrict__ blocksums,
                              int* __restrict__ offsets, int* __restrict__ cursor) {
    __shared__ int s[256];
    int t = threadIdx.x;
    s[t] = (t < SCAN_BLOCKS) ? blocksums[t] : 0;
    __syncthreads();
    for (int off = 1; off < 256; off <<= 1) {
        int v = (t >= off) ? s[t - off] : 0;
        __syncthreads();
        s[t] += v;
        __syncthreads();
    }
    int bo = (blockIdx.x == 0) ? 0 : s[blockIdx.x - 1];
    int i = blockIdx.x * 256 + t;
    if (i < N_NODES) {
        int inc = incl[i];
        int off = bo + inc - deg[i];
        offsets[i] = off;
        cursor[i]  = off;
        if (i == N_NODES - 1) offsets[N_NODES] = bo + inc;
    }
}

__global__ void scatter_kernel(const int* __restrict__ src, const int* __restrict__ dst,
                               int* __restrict__ cursor, int* __restrict__ csr_src) {
    int e = blockIdx.x * blockDim.x + threadIdx.x;
    if (e < N_EDGES) {
        int pos = atomicAdd(&cursor[dst[e]], 1);
        csr_src[pos] = src[e];
    }
}

// ---------------- aggregation v3: wave per node, fp8 gather, 16-deep load pipeline ----------------
// Lane owns D/64 fp8 elements of the row (ushort for D=128, uint for D=256) ->
// one wave-load = one full row. u[16] register buffer = 16 independent loads in flight.

template <int D>
__global__ __launch_bounds__(256) void agg_kernel(const uchar* __restrict__ x,
                                                  const int* __restrict__ offsets,
                                                  const int* __restrict__ csr_src,
                                                  ushort* __restrict__ out) {
    constexpr int BPL = D / 64;   // bytes per lane: 2 or 4
    int node = (blockIdx.x * blockDim.x + threadIdx.x) >> 6;
    int lane = threadIdx.x & 63;
    if (node >= N_NODES) return;
    int j0 = __builtin_amdgcn_readfirstlane(offsets[node]);
    int j1 = __builtin_amdgcn_readfirstlane(offsets[node + 1]);

    float acc[BPL];
#pragma unroll
    for (int i = 0; i < BPL; ++i) acc[i] = 0.f;

    const uchar* base = x + lane * BPL;
    const int il = lane & 15;

    int idxv = (j0 + il < j1) ? csr_src[j0 + il] : 0;

    for (int jb = j0; jb < j1; jb += 16) {
        int idxn = (jb + 16 + il < j1) ? csr_src[jb + 16 + il] : 0;
        int n = j1 - jb; n = (n > 16) ? 16 : n;
        uint u[16];
        if (n == 16) {
#pragma unroll
            for (int i = 0; i < 16; ++i) {
                int s = __shfl(idxv, i);
                if constexpr (BPL == 4)
                    u[i] = *reinterpret_cast<const uint*>(base + (size_t)s * D);
                else
                    u[i] = *reinterpret_cast<const ushort*>(base + (size_t)s * D);
            }
#pragma unroll
            for (int i = 0; i < 16; ++i) {
                if constexpr (BPL == 4) dec4_add(u[i], acc); else dec2_add(u[i], acc);
            }
        } else {
#pragma unroll
            for (int i = 0; i < 16; ++i) {
                if (i < n) {
                    int s = __shfl(idxv, i);
                    if constexpr (BPL == 4)
                        u[i] = *reinterpret_cast<const uint*>(base + (size_t)s * D);
                    else
                        u[i] = *reinterpret_cast<const ushort*>(base + (size_t)s * D);
                }
            }
#pragma unroll
            for (int i = 0; i < 16; ++i) {
                if (i < n) {
                    if constexpr (BPL == 4) dec4_add(u[i], acc); else dec2_add(u[i], acc);
                }
            }
        }
        idxv = idxn;
    }

    // store bf16 row fragment
    if constexpr (BPL == 4) {
        uint2 o;
        o.x = pack_bf16(acc[0], acc[1]);
        o.y = pack_bf16(acc[2], acc[3]);
        *reinterpret_cast<uint2*>(out + (size_t)node * D + lane * 4) = o;
    } else {
        *reinterpret_cast<uint*>(out + (size_t)node * D + lane * 2) = pack_bf16(acc[0], acc[1]);
    }
}

// ---------------- MFMA GEMM1: x1 = relu(agg1 @ W1 + b1) -> fp8 ----------------
// block = 64 rows x 256 cols, 4 waves; wave = 64x64 (4x4 fragments of 16x16x32).

__global__ __launch_bounds__(256) void gemm1_kernel(const ushort* __restrict__ A,
                                                    const ushort* __restrict__ Wt,
                                                    const float* __restrict__ bias,
                                                    uchar* __restrict__ Xout) {
    constexpr int K = NODE_DIM;
    const int lane = threadIdx.x & 63;
    const int wv   = threadIdx.x >> 6;
    const int row0 = blockIdx.x * 64;
    const int col0 = wv * 64;
    const int fr   = lane & 15;
    const int kg   = (lane >> 4) * 8;

    const bf16x8 zero8 = {0, 0, 0, 0, 0, 0, 0, 0};
    f32x4 acc[4][4];
#pragma unroll
    for (int rt = 0; rt < 4; ++rt)
#pragma unroll
        for (int ct = 0; ct < 4; ++ct)
            acc[rt][ct] = (f32x4){0.f, 0.f, 0.f, 0.f};

#pragma unroll
    for (int k0 = 0; k0 < K; k0 += 32) {
        bf16x8 af[4], bfv[4];
#pragma unroll
        for (int rt = 0; rt < 4; ++rt) {
            int r = row0 + rt * 16 + fr;
            af[rt] = (r < N_NODES)
                   ? *reinterpret_cast<const bf16x8*>(A + (size_t)r * K + k0 + kg)
                   : zero8;
        }
#pragma unroll
        for (int ct = 0; ct < 4; ++ct) {
            int c = col0 + ct * 16 + fr;
            bfv[ct] = *reinterpret_cast<const bf16x8*>(Wt + (size_t)c * K + k0 + kg);
        }
#pragma unroll
        for (int rt = 0; rt < 4; ++rt)
#pragma unroll
            for (int ct = 0; ct < 4; ++ct)
                acc[rt][ct] = __builtin_amdgcn_mfma_f32_16x16x32_bf16(af[rt], bfv[ct], acc[rt][ct], 0, 0, 0);
    }

    float bcol[4];
#pragma unroll
    for (int ct = 0; ct < 4; ++ct) bcol[ct] = bias[col0 + ct * 16 + fr];
    const int mrow = (lane >> 4) * 4;

#pragma unroll
    for (int rt = 0; rt < 4; ++rt) {
#pragma unroll
        for (int e = 0; e < 4; ++e) {
            int m = row0 + rt * 16 + mrow + e;
            if (m < N_NODES) {
#pragma unroll
                for (int ct = 0; ct < 4; ++ct) {
                    float v = fmaxf(acc[rt][ct][e] + bcol[ct], 0.f);
                    Xout[(size_t)m * HIDDEN + col0 + ct * 16 + fr] = enc1(v);
                }
            }
        }
    }
}

// ---------------- MFMA GEMM2 + mean-pool: pooled += colsum(relu(agg2 @ W2 + b2)) ----------------

__global__ __launch_bounds__(256) void gemm2_kernel(const ushort* __restrict__ A,
                                                    const ushort* __restrict__ Wt,
                                                    const float* __restrict__ bias,
                                                    float* __restrict__ pooled) {
    constexpr int K = HIDDEN;
    const int lane = threadIdx.x & 63;
    const int wv   = threadIdx.x >> 6;
    const int row0 = blockIdx.x * 64;
    const int col0 = wv * 64;
    const int fr   = lane & 15;
    const int kg   = (lane >> 4) * 8;

    const bf16x8 zero8 = {0, 0, 0, 0, 0, 0, 0, 0};
    f32x4 acc[4][4];
#pragma unroll
    for (int rt = 0; rt < 4; ++rt)
#pragma unroll
        for (int ct = 0; ct < 4; ++ct)
            acc[rt][ct] = (f32x4){0.f, 0.f, 0.f, 0.f};

#pragma unroll
    for (int k0 = 0; k0 < K; k0 += 32) {
        bf16x8 af[4], bfv[4];
#pragma unroll
        for (int rt = 0; rt < 4; ++rt) {
            int r = row0 + rt * 16 + fr;
            af[rt] = (r < N_NODES)
                   ? *reinterpret_cast<const bf16x8*>(A + (size_t)r * K + k0 + kg)
                   : zero8;
        }
#pragma unroll
        for (int ct = 0; ct < 4; ++ct) {
            int c = col0 + ct * 16 + fr;
            bfv[ct] = *reinterpret_cast<const bf16x8*>(Wt + (size_t)c * K + k0 + kg);
        }
#pragma unroll
        for (int rt = 0; rt < 4; ++rt)
#pragma unroll
            for (int ct = 0; ct < 4; ++ct)
                acc[rt][ct] = __builtin_amdgcn_mfma_f32_16x16x32_bf16(af[rt], bfv[ct], acc[rt][ct], 0, 0, 0);
    }

    float bcol[4];
#pragma unroll
    for (int ct = 0; ct < 4; ++ct) bcol[ct] = bias[col0 + ct * 16 + fr];
    const int mrow = (lane >> 4) * 4;

    float cs[4] = {0.f, 0.f, 0.f, 0.f};
#pragma unroll
    for (int rt = 0; rt < 4; ++rt) {
#pragma unroll
        for (int e = 0; e < 4; ++e) {
            int m = row0 + rt * 16 + mrow + e;
            if (m < N_NODES) {
#pragma unroll
                for (int ct = 0; ct < 4; ++ct)
                    cs[ct] += fmaxf(acc[rt][ct][e] + bcol[ct], 0.f);
            }
        }
    }
#pragma unroll
    for (int ct = 0; ct < 4; ++ct) {
        cs[ct] += __shfl_xor(cs[ct], 16);
        cs[ct] += __shfl_xor(cs[ct], 32);
    }
    if (lane < 16) {
#pragma unroll
        for (int ct = 0; ct < 4; ++ct)
            atomicAdd(&pooled[col0 + ct * 16 + lane], cs[ct]);
    }
}

// ---------------- head MLP ----------------

__global__ void head_kernel(const float* __restrict__ pooled_sum, const float* __restrict__ cond,
                            const float* __restrict__ Wfc, const float* __restrict__ bfc,
                            const float* __restrict__ Wmean, const float* __restrict__ bmean,
                            const float* __restrict__ Wlogvar, const float* __restrict__ blogvar,
                            float* __restrict__ out) {
    __shared__ float v[HIDDEN + COND];
    __shared__ float h[LATENT];
    int t = threadIdx.x;
    if (t < HIDDEN) v[t] = pooled_sum[t] * (1.0f / N_NODES);
    if (t < COND) v[HIDDEN + t] = cond[t];
    __syncthreads();
    if (t < LATENT) {
        float s = bfc[t];
        for (int k = 0; k < HIDDEN + COND; ++k) s += v[k] * Wfc[k * LATENT + t];
        h[t] = fmaxf(s, 0.f);
    }
    __syncthreads();
    if (t < LATENT) {
        float s = bmean[t];
        for (int k = 0; k < LATENT; ++k) s += h[k] * Wmean[k * LATENT + t];
        out[t] = s;
    } else {
        int j = t - LATENT;
        float s = blogvar[j];
        for (int k = 0; k < LATENT; ++k) s += h[k] * Wlogvar[k * LATENT + j];
        out[LATENT + j] = s;
    }
}

// ---------------- launch ----------------

extern "C" void kernel_launch(void* const* d_in, const int* in_sizes, int n_in,
                              void* d_out, int out_size, void* d_ws, size_t ws_size,
                              hipStream_t stream) {
    const float* node_features = (const float*)d_in[0];
    const float* conditions    = (const float*)d_in[1];
    const int*   src           = (const int*)d_in[2];
    const int*   dst           = (const int*)d_in[3];
    const float* W1  = (const float*)d_in[4];
    const float* b1  = (const float*)d_in[5];
    const float* W2  = (const float*)d_in[6];
    const float* b2  = (const float*)d_in[7];
    const float* Wfc = (const float*)d_in[8];
    const float* bfc = (const float*)d_in[9];
    const float* Wmean   = (const float*)d_in[10];
    const float* bmean   = (const float*)d_in[11];
    const float* Wlogvar = (const float*)d_in[12];
    const float* blogvar = (const float*)d_in[13];
    float* out = (float*)d_out;

    size_t o = 0;
    auto alloc = [&](size_t bytes) {
        void* p = (char*)d_ws + o;
        o += (bytes + 255) & ~(size_t)255;
        return p;
    };
    int* deg       = (int*)alloc((size_t)N_NODES * 4);
    int* offsets   = (int*)alloc((size_t)(N_NODES + 1) * 4);
    int* cursor    = (int*)alloc((size_t)N_NODES * 4);
    int* incl      = (int*)alloc((size_t)N_NODES * 4);
    int* blocksums = (int*)alloc((size_t)SCAN_BLOCKS * 4);
    int* csr_src   = (int*)alloc((size_t)N_EDGES * 4);
    float* pooled  = (float*)alloc(HIDDEN * 4);
    ushort* Wt1    = (ushort*)alloc((size_t)HIDDEN * NODE_DIM * 2);   // 64 KB
    ushort* Wt2    = (ushort*)alloc((size_t)HIDDEN * HIDDEN * 2);     // 128 KB
    uchar* nf_fp8  = (uchar*)alloc((size_t)N_NODES * NODE_DIM);       // 6.4 MB
    uchar* x1_fp8  = (uchar*)alloc((size_t)N_NODES * HIDDEN);         // 12.8 MB
    ushort* agg1   = (ushort*)alloc((size_t)N_NODES * NODE_DIM * 2);  // 12.8 MB
    ushort* agg2   = (ushort*)alloc((size_t)N_NODES * HIDDEN * 2);    // 25.6 MB

    prep_kernel<<<(PREP4 + 255) / 256, 256, 0, stream>>>(
        node_features, W1, W2, nf_fp8, Wt1, Wt2, deg, pooled);

    hist_kernel<<<N_EDGES / 256, 256, 0, stream>>>(dst, deg);
    scan_a_kernel<<<SCAN_BLOCKS, 256, 0, stream>>>(deg, incl, blocksums);
    scan_c_kernel<<<SCAN_BLOCKS, 256, 0, stream>>>(deg, incl, blocksums, offsets, cursor);
    scatter_kernel<<<N_EDGES / 256, 256, 0, stream>>>(src, dst, cursor, csr_src);

    const int AGG_GRID  = (N_NODES * 64 + 255) / 256;  // 12500 (wave per node)
    const int GEMM_GRID = (N_NODES + 63) / 64;         // 782

    // layer 1: gather fp8 nf -> agg1 (bf16) -> MFMA -> x1 (fp8)
    agg_kernel<NODE_DIM><<<AGG_GRID, 256, 0, stream>>>(nf_fp8, offsets, csr_src, agg1);
    gemm1_kernel<<<GEMM_GRID, 256, 0, stream>>>(agg1, Wt1, b1, x1_fp8);

    // layer 2: gather fp8 x1 -> agg2 (bf16) -> MFMA + pooled colsum
    agg_kernel<HIDDEN><<<AGG_GRID, 256, 0, stream>>>(x1_fp8, offsets, csr_src, agg2);
    gemm2_kernel<<<GEMM_GRID, 256, 0, stream>>>(agg2, Wt2, b2, pooled);

    head_kernel<<<1, 256, 0, stream>>>(pooled, conditions, Wfc, bfc,
                                       Wmean, bmean, Wlogvar, blogvar, out);
}

// Round 8
// 215.052 us; speedup vs baseline: 3.1546x; 1.2183x over previous
//
#include <hip/hip_runtime.h>

#define N_NODES   50000
#define N_EDGES   800000
#define NODE_DIM  128
#define HIDDEN    256
#define LATENT    128
#define COND      5

#define SCAN_BLOCKS ((N_NODES + 255) / 256)   // 196
#define NB          196                        // buckets: dst>>8 (256-node ranges)
#define P1_CHUNK    4096
#define P1_GRID     ((N_EDGES + P1_CHUNK - 1) / P1_CHUNK)  // 196

typedef unsigned int uint;
typedef unsigned short ushort;
typedef unsigned char uchar;

typedef __attribute__((ext_vector_type(8))) short bf16x8;
typedef __attribute__((ext_vector_type(4))) float f32x4;

static __device__ __forceinline__ ushort f32_to_bf16(float f) {
    union { float f; uint u; } v; v.f = f;
    uint r = v.u + 0x7FFF + ((v.u >> 16) & 1);   // RNE
    return (ushort)(r >> 16);
}
static __device__ __forceinline__ uint pack_bf16(float lo, float hi) {
    return (uint)f32_to_bf16(lo) | ((uint)f32_to_bf16(hi) << 16);
}

// ---------------- fp8 e4m3 helpers (HW cvt with software fallback) ----------------

#if __has_builtin(__builtin_amdgcn_cvt_pk_f32_fp8) && __has_builtin(__builtin_amdgcn_cvt_pk_fp8_f32)
#define HW_FP8 1
#endif

#ifndef HW_FP8
static __device__ __forceinline__ float dec1_fp8(uint b) {
    uint sgn = b & 0x80, mag = b & 0x7f;
    float v;
    if (mag >= 8) {
        union { uint u; float f; } t;
        t.u = (((mag >> 3) + 120) << 23) | ((mag & 7) << 20);
        v = t.f;
    } else {
        v = (float)mag * 0.001953125f;   // 2^-9
    }
    return sgn ? -v : v;
}
static __device__ __forceinline__ uchar enc1_fp8(float f) {
    float a = fabsf(f);
    uint s = (f < 0.f) ? 0x80u : 0u;
    if (!(a >= 0.015625f)) {
        int q = (int)(a * 512.f + 0.5f);
        if (q > 7) q = 7;
        return (uchar)(s | (uint)q);
    }
    if (a >= 448.f) return (uchar)(s | 0x7E);
    union { float f; uint u; } t; t.f = a;
    uint e = (t.u >> 23) - 120;
    uint m = (t.u >> 20) & 7;
    uint rem = t.u & 0xFFFFF;
    uint v = (e << 3) | m;
    if (rem > 0x80000 || (rem == 0x80000 && (v & 1))) v++;
    if (v > 0x7E) v = 0x7E;
    return (uchar)(s | v);
}
#endif

static __device__ __forceinline__ void dec4_add(uint u, float* acc) {
#ifdef HW_FP8
    auto lo = __builtin_amdgcn_cvt_pk_f32_fp8((int)u, false);
    auto hi = __builtin_amdgcn_cvt_pk_f32_fp8((int)u, true);
    acc[0] += lo[0]; acc[1] += lo[1]; acc[2] += hi[0]; acc[3] += hi[1];
#else
    acc[0] += dec1_fp8(u & 0xff);
    acc[1] += dec1_fp8((u >> 8) & 0xff);
    acc[2] += dec1_fp8((u >> 16) & 0xff);
    acc[3] += dec1_fp8(u >> 24);
#endif
}
static __device__ __forceinline__ void dec2_add(uint u, float* acc) {
#ifdef HW_FP8
    auto lo = __builtin_amdgcn_cvt_pk_f32_fp8((int)u, false);
    acc[0] += lo[0]; acc[1] += lo[1];
#else
    acc[0] += dec1_fp8(u & 0xff);
    acc[1] += dec1_fp8((u >> 8) & 0xff);
#endif
}
static __device__ __forceinline__ uint enc2_fp8(float a, float b) {
#ifdef HW_FP8
    return (uint)__builtin_amdgcn_cvt_pk_fp8_f32(a, b, 0, false) & 0xFFFFu;
#else
    return (uint)enc1_fp8(a) | ((uint)enc1_fp8(b) << 8);
#endif
}
static __device__ __forceinline__ uchar enc1(float v) {
#ifdef HW_FP8
    return (uchar)(__builtin_amdgcn_cvt_pk_fp8_f32(v, v, 0, false) & 0xff);
#else
    return enc1_fp8(v);
#endif
}

// ---------------- prep: nf -> fp8, W transpose (bf16), deg/pooled zero ----------------

#define NF4   (N_NODES * NODE_DIM / 4)            // 1,600,000
#define PREP1 (NF4 + NODE_DIM * HIDDEN)           // + 32768
#define PREP2 (PREP1 + HIDDEN * HIDDEN)           // + 65536
#define PREP3 (PREP2 + N_NODES)                   // + 50000 (deg zero)
#define PREP4 (PREP3 + HIDDEN)                    // + 256 (pooled zero)

__global__ void prep_kernel(const float* __restrict__ nf,
                            const float* __restrict__ W1, const float* __restrict__ W2,
                            uchar* __restrict__ nf_fp8,
                            ushort* __restrict__ Wt1, ushort* __restrict__ Wt2,
                            int* __restrict__ deg, float* __restrict__ pooled) {
    int id = blockIdx.x * blockDim.x + threadIdx.x;
    if (id < NF4) {
        float4 v = reinterpret_cast<const float4*>(nf)[id];
        uint w = enc2_fp8(v.x, v.y) | (enc2_fp8(v.z, v.w) << 16);
        reinterpret_cast<uint*>(nf_fp8)[id] = w;
    } else if (id < PREP1) {
        int i = id - NF4;
        int k = i >> 8, c = i & 255;
        Wt1[c * NODE_DIM + k] = f32_to_bf16(W1[i]);
    } else if (id < PREP2) {
        int i = id - PREP1;
        int k = i >> 8, c = i & 255;
        Wt2[c * HIDDEN + k] = f32_to_bf16(W2[i]);
    } else if (id < PREP3) {
        deg[id - PREP2] = 0;
    } else if (id < PREP4) {
        pooled[id - PREP3] = 0.f;
    }
}

// ---------------- CSR build ----------------

__global__ void hist_kernel(const int* __restrict__ dst, int* __restrict__ deg) {
    int e = blockIdx.x * blockDim.x + threadIdx.x;
    if (e < N_EDGES) atomicAdd(&deg[dst[e]], 1);
}

__global__ void scan_a_kernel(const int* __restrict__ deg, int* __restrict__ incl,
                              int* __restrict__ blocksums) {
    int i = blockIdx.x * 256 + threadIdx.x;
    int lane = threadIdx.x & 63;
    int w    = threadIdx.x >> 6;
    int v = (i < N_NODES) ? deg[i] : 0;
    int s = v;
#pragma unroll
    for (int d = 1; d < 64; d <<= 1) {
        int t = __shfl_up(s, d);
        if (lane >= d) s += t;
    }
    __shared__ int wsum[4];
    if (lane == 63) wsum[w] = s;
    __syncthreads();
    int add = 0;
    for (int k = 0; k < w; ++k) add += wsum[k];
    s += add;
    if (i < N_NODES) incl[i] = s;
    if (threadIdx.x == 255) blocksums[blockIdx.x] = s;
}

// offsets = global exclusive scan; also init per-bucket cursor bcursor[b] = offsets[b*256]
__global__ void scan_c_kernel(const int* __restrict__ deg, const int* __restrict__ incl,
                              const int* __restrict__ blocksums,
                              int* __restrict__ offsets, int* __restrict__ bcursor) {
    __shared__ int s[256];
    int t = threadIdx.x;
    s[t] = (t < SCAN_BLOCKS) ? blocksums[t] : 0;
    __syncthreads();
    for (int off = 1; off < 256; off <<= 1) {
        int v = (t >= off) ? s[t - off] : 0;
        __syncthreads();
        s[t] += v;
        __syncthreads();
    }
    int bo = (blockIdx.x == 0) ? 0 : s[blockIdx.x - 1];
    int i = blockIdx.x * 256 + t;
    if (i < N_NODES) {
        int inc = incl[i];
        int off = bo + inc - deg[i];
        offsets[i] = off;
        if ((i & 255) == 0) bcursor[i >> 8] = off;   // bucket base
        if (i == N_NODES - 1) offsets[N_NODES] = bo + inc;
    }
}

// ---------------- pass 1: bucket multi-split (LDS-batched) ----------------
// Packs (src | dst<<16) into pair_buf, bucket-contiguous (bucket = dst>>8).

__global__ __launch_bounds__(256) void bucket_kernel(const int* __restrict__ src,
                                                     const int* __restrict__ dst,
                                                     int* __restrict__ bcursor,
                                                     uint* __restrict__ pair_buf) {
    __shared__ int cnt[NB];
    __shared__ int gbase[NB];
    const int t = threadIdx.x;
    for (int i = t; i < NB; i += 256) cnt[i] = 0;
    __syncthreads();

    const int base = blockIdx.x * P1_CHUNK;
    uint pk[16];
    int  bk[16], lr[16];
    bool ok[16];
#pragma unroll
    for (int i = 0; i < 16; ++i) {
        int e = base + i * 256 + t;
        ok[i] = e < N_EDGES;
        if (ok[i]) {
            int s = src[e], d = dst[e];
            pk[i] = (uint)s | ((uint)d << 16);
            bk[i] = d >> 8;
        }
    }
#pragma unroll
    for (int i = 0; i < 16; ++i)
        if (ok[i]) lr[i] = atomicAdd(&cnt[bk[i]], 1);
    __syncthreads();
    if (t < NB) {
        int c = cnt[t];
        gbase[t] = (c > 0) ? atomicAdd(&bcursor[t], c) : 0;
    }
    __syncthreads();
#pragma unroll
    for (int i = 0; i < 16; ++i)
        if (ok[i]) pair_buf[gbase[bk[i]] + lr[i]] = pk[i];
}

// ---------------- pass 2: block-local CSR scatter (one block per bucket) ----------------

__global__ __launch_bounds__(256) void csr_kernel(const uint* __restrict__ pair_buf,
                                                  const int* __restrict__ offsets,
                                                  ushort* __restrict__ csr) {
    __shared__ int loff[257];
    __shared__ int lcur[256];
    const int b  = blockIdx.x;
    const int t  = threadIdx.x;
    const int n0 = b << 8;
    int node = n0 + t;
    loff[t] = offsets[node < N_NODES ? node : N_NODES];
    if (t == 0) {
        int ne = n0 + 256;
        loff[256] = offsets[ne < N_NODES ? ne : N_NODES];
    }
    lcur[t] = 0;
    __syncthreads();
    const int e0 = loff[0], e1 = loff[256];
    for (int j = e0 + t; j < e1; j += 256) {
        uint p = pair_buf[j];
        int dl = (int)(p >> 16) - n0;
        int r = atomicAdd(&lcur[dl], 1);
        csr[loff[dl] + r] = (ushort)(p & 0xFFFFu);
    }
}

// ---------------- aggregation: wave per node, fp8 gather, 16-deep load pipeline ----------------

template <int D>
__global__ __launch_bounds__(256) void agg_kernel(const uchar* __restrict__ x,
                                                  const int* __restrict__ offsets,
                                                  const ushort* __restrict__ csr,
                                                  ushort* __restrict__ out) {
    constexpr int BPL = D / 64;   // bytes per lane: 2 or 4
    int node = (blockIdx.x * blockDim.x + threadIdx.x) >> 6;
    int lane = threadIdx.x & 63;
    if (node >= N_NODES) return;
    int j0 = __builtin_amdgcn_readfirstlane(offsets[node]);
    int j1 = __builtin_amdgcn_readfirstlane(offsets[node + 1]);

    float acc[BPL];
#pragma unroll
    for (int i = 0; i < BPL; ++i) acc[i] = 0.f;

    const uchar* base = x + lane * BPL;
    const int il = lane & 15;

    int idxv = (j0 + il < j1) ? (int)csr[j0 + il] : 0;

    for (int jb = j0; jb < j1; jb += 16) {
        int idxn = (jb + 16 + il < j1) ? (int)csr[jb + 16 + il] : 0;
        int n = j1 - jb; n = (n > 16) ? 16 : n;
        uint u[16];
        if (n == 16) {
#pragma unroll
            for (int i = 0; i < 16; ++i) {
                int s = __shfl(idxv, i);
                if constexpr (BPL == 4)
                    u[i] = *reinterpret_cast<const uint*>(base + (size_t)s * D);
                else
                    u[i] = *reinterpret_cast<const ushort*>(base + (size_t)s * D);
            }
#pragma unroll
            for (int i = 0; i < 16; ++i) {
                if constexpr (BPL == 4) dec4_add(u[i], acc); else dec2_add(u[i], acc);
            }
        } else {
#pragma unroll
            for (int i = 0; i < 16; ++i) {
                if (i < n) {
                    int s = __shfl(idxv, i);
                    if constexpr (BPL == 4)
                        u[i] = *reinterpret_cast<const uint*>(base + (size_t)s * D);
                    else
                        u[i] = *reinterpret_cast<const ushort*>(base + (size_t)s * D);
                }
            }
#pragma unroll
            for (int i = 0; i < 16; ++i) {
                if (i < n) {
                    if constexpr (BPL == 4) dec4_add(u[i], acc); else dec2_add(u[i], acc);
                }
            }
        }
        idxv = idxn;
    }

    if constexpr (BPL == 4) {
        uint2 o;
        o.x = pack_bf16(acc[0], acc[1]);
        o.y = pack_bf16(acc[2], acc[3]);
        *reinterpret_cast<uint2*>(out + (size_t)node * D + lane * 4) = o;
    } else {
        *reinterpret_cast<uint*>(out + (size_t)node * D + lane * 2) = pack_bf16(acc[0], acc[1]);
    }
}

// ---------------- MFMA GEMM1: x1 = relu(agg1 @ W1 + b1) -> fp8 ----------------

__global__ __launch_bounds__(256) void gemm1_kernel(const ushort* __restrict__ A,
                                                    const ushort* __restrict__ Wt,
                                                    const float* __restrict__ bias,
                                                    uchar* __restrict__ Xout) {
    constexpr int K = NODE_DIM;
    const int lane = threadIdx.x & 63;
    const int wv   = threadIdx.x >> 6;
    const int row0 = blockIdx.x * 64;
    const int col0 = wv * 64;
    const int fr   = lane & 15;
    const int kg   = (lane >> 4) * 8;

    const bf16x8 zero8 = {0, 0, 0, 0, 0, 0, 0, 0};
    f32x4 acc[4][4];
#pragma unroll
    for (int rt = 0; rt < 4; ++rt)
#pragma unroll
        for (int ct = 0; ct < 4; ++ct)
            acc[rt][ct] = (f32x4){0.f, 0.f, 0.f, 0.f};

#pragma unroll
    for (int k0 = 0; k0 < K; k0 += 32) {
        bf16x8 af[4], bfv[4];
#pragma unroll
        for (int rt = 0; rt < 4; ++rt) {
            int r = row0 + rt * 16 + fr;
            af[rt] = (r < N_NODES)
                   ? *reinterpret_cast<const bf16x8*>(A + (size_t)r * K + k0 + kg)
                   : zero8;
        }
#pragma unroll
        for (int ct = 0; ct < 4; ++ct) {
            int c = col0 + ct * 16 + fr;
            bfv[ct] = *reinterpret_cast<const bf16x8*>(Wt + (size_t)c * K + k0 + kg);
        }
#pragma unroll
        for (int rt = 0; rt < 4; ++rt)
#pragma unroll
            for (int ct = 0; ct < 4; ++ct)
                acc[rt][ct] = __builtin_amdgcn_mfma_f32_16x16x32_bf16(af[rt], bfv[ct], acc[rt][ct], 0, 0, 0);
    }

    float bcol[4];
#pragma unroll
    for (int ct = 0; ct < 4; ++ct) bcol[ct] = bias[col0 + ct * 16 + fr];
    const int mrow = (lane >> 4) * 4;

#pragma unroll
    for (int rt = 0; rt < 4; ++rt) {
#pragma unroll
        for (int e = 0; e < 4; ++e) {
            int m = row0 + rt * 16 + mrow + e;
            if (m < N_NODES) {
#pragma unroll
                for (int ct = 0; ct < 4; ++ct) {
                    float v = fmaxf(acc[rt][ct][e] + bcol[ct], 0.f);
                    Xout[(size_t)m * HIDDEN + col0 + ct * 16 + fr] = enc1(v);
                }
            }
        }
    }
}

// ---------------- MFMA GEMM2 + mean-pool ----------------

__global__ __launch_bounds__(256) void gemm2_kernel(const ushort* __restrict__ A,
                                                    const ushort* __restrict__ Wt,
                                                    const float* __restrict__ bias,
                                                    float* __restrict__ pooled) {
    constexpr int K = HIDDEN;
    const int lane = threadIdx.x & 63;
    const int wv   = threadIdx.x >> 6;
    const int row0 = blockIdx.x * 64;
    const int col0 = wv * 64;
    const int fr   = lane & 15;
    const int kg   = (lane >> 4) * 8;

    const bf16x8 zero8 = {0, 0, 0, 0, 0, 0, 0, 0};
    f32x4 acc[4][4];
#pragma unroll
    for (int rt = 0; rt < 4; ++rt)
#pragma unroll
        for (int ct = 0; ct < 4; ++ct)
            acc[rt][ct] = (f32x4){0.f, 0.f, 0.f, 0.f};

#pragma unroll
    for (int k0 = 0; k0 < K; k0 += 32) {
        bf16x8 af[4], bfv[4];
#pragma unroll
        for (int rt = 0; rt < 4; ++rt) {
            int r = row0 + rt * 16 + fr;
            af[rt] = (r < N_NODES)
                   ? *reinterpret_cast<const bf16x8*>(A + (size_t)r * K + k0 + kg)
                   : zero8;
        }
#pragma unroll
        for (int ct = 0; ct < 4; ++ct) {
            int c = col0 + ct * 16 + fr;
            bfv[ct] = *reinterpret_cast<const bf16x8*>(Wt + (size_t)c * K + k0 + kg);
        }
#pragma unroll
        for (int rt = 0; rt < 4; ++rt)
#pragma unroll
            for (int ct = 0; ct < 4; ++ct)
                acc[rt][ct] = __builtin_amdgcn_mfma_f32_16x16x32_bf16(af[rt], bfv[ct], acc[rt][ct], 0, 0, 0);
    }

    float bcol[4];
#pragma unroll
    for (int ct = 0; ct < 4; ++ct) bcol[ct] = bias[col0 + ct * 16 + fr];
    const int mrow = (lane >> 4) * 4;

    float cs[4] = {0.f, 0.f, 0.f, 0.f};
#pragma unroll
    for (int rt = 0; rt < 4; ++rt) {
#pragma unroll
        for (int e = 0; e < 4; ++e) {
            int m = row0 + rt * 16 + mrow + e;
            if (m < N_NODES) {
#pragma unroll
                for (int ct = 0; ct < 4; ++ct)
                    cs[ct] += fmaxf(acc[rt][ct][e] + bcol[ct], 0.f);
            }
        }
    }
#pragma unroll
    for (int ct = 0; ct < 4; ++ct) {
        cs[ct] += __shfl_xor(cs[ct], 16);
        cs[ct] += __shfl_xor(cs[ct], 32);
    }
    if (lane < 16) {
#pragma unroll
        for (int ct = 0; ct < 4; ++ct)
            atomicAdd(&pooled[col0 + ct * 16 + lane], cs[ct]);
    }
}

// ---------------- head MLP ----------------

__global__ void head_kernel(const float* __restrict__ pooled_sum, const float* __restrict__ cond,
                            const float* __restrict__ Wfc, const float* __restrict__ bfc,
                            const float* __restrict__ Wmean, const float* __restrict__ bmean,
                            const float* __restrict__ Wlogvar, const float* __restrict__ blogvar,
                            float* __restrict__ out) {
    __shared__ float v[HIDDEN + COND];
    __shared__ float h[LATENT];
    int t = threadIdx.x;
    if (t < HIDDEN) v[t] = pooled_sum[t] * (1.0f / N_NODES);
    if (t < COND) v[HIDDEN + t] = cond[t];
    __syncthreads();
    if (t < LATENT) {
        float s = bfc[t];
        for (int k = 0; k < HIDDEN + COND; ++k) s += v[k] * Wfc[k * LATENT + t];
        h[t] = fmaxf(s, 0.f);
    }
    __syncthreads();
    if (t < LATENT) {
        float s = bmean[t];
        for (int k = 0; k < LATENT; ++k) s += h[k] * Wmean[k * LATENT + t];
        out[t] = s;
    } else {
        int j = t - LATENT;
        float s = blogvar[j];
        for (int k = 0; k < LATENT; ++k) s += h[k] * Wlogvar[k * LATENT + j];
        out[LATENT + j] = s;
    }
}

// ---------------- launch ----------------

extern "C" void kernel_launch(void* const* d_in, const int* in_sizes, int n_in,
                              void* d_out, int out_size, void* d_ws, size_t ws_size,
                              hipStream_t stream) {
    const float* node_features = (const float*)d_in[0];
    const float* conditions    = (const float*)d_in[1];
    const int*   src           = (const int*)d_in[2];
    const int*   dst           = (const int*)d_in[3];
    const float* W1  = (const float*)d_in[4];
    const float* b1  = (const float*)d_in[5];
    const float* W2  = (const float*)d_in[6];
    const float* b2  = (const float*)d_in[7];
    const float* Wfc = (const float*)d_in[8];
    const float* bfc = (const float*)d_in[9];
    const float* Wmean   = (const float*)d_in[10];
    const float* bmean   = (const float*)d_in[11];
    const float* Wlogvar = (const float*)d_in[12];
    const float* blogvar = (const float*)d_in[13];
    float* out = (float*)d_out;

    size_t o = 0;
    auto alloc = [&](size_t bytes) {
        void* p = (char*)d_ws + o;
        o += (bytes + 255) & ~(size_t)255;
        return p;
    };
    int* deg       = (int*)alloc((size_t)N_NODES * 4);
    int* offsets   = (int*)alloc((size_t)(N_NODES + 1) * 4);
    int* incl      = (int*)alloc((size_t)N_NODES * 4);
    int* blocksums = (int*)alloc((size_t)SCAN_BLOCKS * 4);
    int* bcursor   = (int*)alloc((size_t)NB * 4);
    uint* pair_buf = (uint*)alloc((size_t)N_EDGES * 4);     // 3.2 MB
    ushort* csr    = (ushort*)alloc((size_t)N_EDGES * 2);   // 1.6 MB
    float* pooled  = (float*)alloc(HIDDEN * 4);
    ushort* Wt1    = (ushort*)alloc((size_t)HIDDEN * NODE_DIM * 2);
    ushort* Wt2    = (ushort*)alloc((size_t)HIDDEN * HIDDEN * 2);
    uchar* nf_fp8  = (uchar*)alloc((size_t)N_NODES * NODE_DIM);       // 6.4 MB
    uchar* x1_fp8  = (uchar*)alloc((size_t)N_NODES * HIDDEN);         // 12.8 MB
    ushort* agg1   = (ushort*)alloc((size_t)N_NODES * NODE_DIM * 2);  // 12.8 MB
    ushort* agg2   = (ushort*)alloc((size_t)N_NODES * HIDDEN * 2);    // 25.6 MB

    prep_kernel<<<(PREP4 + 255) / 256, 256, 0, stream>>>(
        node_features, W1, W2, nf_fp8, Wt1, Wt2, deg, pooled);

    hist_kernel<<<N_EDGES / 256, 256, 0, stream>>>(dst, deg);
    scan_a_kernel<<<SCAN_BLOCKS, 256, 0, stream>>>(deg, incl, blocksums);
    scan_c_kernel<<<SCAN_BLOCKS, 256, 0, stream>>>(deg, incl, blocksums, offsets, bcursor);
    bucket_kernel<<<P1_GRID, 256, 0, stream>>>(src, dst, bcursor, pair_buf);
    csr_kernel<<<NB, 256, 0, stream>>>(pair_buf, offsets, csr);

    const int AGG_GRID  = (N_NODES * 64 + 255) / 256;  // wave per node
    const int GEMM_GRID = (N_NODES + 63) / 64;

    agg_kernel<NODE_DIM><<<AGG_GRID, 256, 0, stream>>>(nf_fp8, offsets, csr, agg1);
    gemm1_kernel<<<GEMM_GRID, 256, 0, stream>>>(agg1, Wt1, b1, x1_fp8);

    agg_kernel<HIDDEN><<<AGG_GRID, 256, 0, stream>>>(x1_fp8, offsets, csr, agg2);
    gemm2_kernel<<<GEMM_GRID, 256, 0, stream>>>(agg2, Wt2, b2, pooled);

    head_kernel<<<1, 256, 0, stream>>>(pooled, conditions, Wfc, bfc,
                                       Wmean, bmean, Wlogvar, blogvar, out);
}